// Round 1
// baseline (282.111 us; speedup 1.0000x reference)
//
#include <hip/hip_runtime.h>

#define TSEQ 111
#define L2E 1.44269504088896340736f

using f32x4  = __attribute__((ext_vector_type(4))) float;
using short8 = __attribute__((ext_vector_type(8))) short;

union FragCast { unsigned u[4]; short8 s; };

__device__ __forceinline__ short8 frag(const unsigned u[4]) {
  FragCast f;
  f.u[0] = u[0]; f.u[1] = u[1]; f.u[2] = u[2]; f.u[3] = u[3];
  return f.s;
}

__device__ __forceinline__ float fexp2(float x) { return __builtin_amdgcn_exp2f(x); }
__device__ __forceinline__ float frcp(float x)  { return __builtin_amdgcn_rcpf(x); }
// sigmoid(z) given zs = z*log2(e)
__device__ __forceinline__ float sigm2(float zs) { return frcp(1.f + fexp2(-zs)); }
// tanh(z) given zs = z*log2(e)
__device__ __forceinline__ float tanh2(float zs) { return 1.f - 2.f * frcp(1.f + fexp2(zs + zs)); }

// pack fp32 -> (bf16 hi | bf16 lo) in one u32 (hi in low 16, lo in high 16)
__device__ __forceinline__ unsigned packhl(float h) {
  unsigned b  = __float_as_uint(h);
  unsigned hi = b & 0xffff0000u;
  float lo    = h - __uint_as_float(hi);
  return (hi >> 16) | (__float_as_uint(lo) & 0xffff0000u);
}

// layout: block = 4 waves (one per LSTM layer), 16 batch rows per block.
// wave-level pipeline: at superstep s, wave l computes timestep t = s - l.
// A-frag (16x32 bf16): lane: row = lane&15, k = 8*(lane>>4)+e
// B-frag:              lane: col = lane&15, k = 8*(lane>>4)+e
// C-frag (16x16 f32):  lane: col = lane&15, row = 4*(lane>>4)+e   (m89-verified)
__global__ __launch_bounds__(256, 2) void lstm_fused(
    const int* __restrict__ x, const float* __restrict__ emb,
    const float* __restrict__ Wih, const float* __restrict__ Whh,
    const float* __restrict__ bih, const float* __restrict__ bhh,
    const float* __restrict__ Wa, const float* __restrict__ W1,
    const float* __restrict__ b1, const float* __restrict__ W2,
    const float* __restrict__ b2, float* __restrict__ out)
{
  // [parity][layer][16 rows][32 cols] packed-u32 h values, 16B-granularity XOR swizzle
  __shared__ unsigned hbuf[2 * 4 * 512];

  const int tid  = threadIdx.x;
  const int wv   = tid >> 6;     // layer id 0..3
  const int lane = tid & 63;
  const int c    = lane & 15;    // col-in-tile / A-row
  const int q    = lane >> 4;    // k-octet / C-row-quad
  const int rowbase = blockIdx.x * 16;

  for (int i = tid; i < 2 * 4 * 512; i += 256) hbuf[i] = 0u;

  // ---- weights -> register-resident B-fragments, hi/lo bf16 split, scaled by log2(e)
  unsigned bwh[2][8][4], bwl[2][8][4];
  {
    const float* WI = Wih + wv * 4096;
    const float* WH = Whh + wv * 4096;
#pragma unroll
    for (int kt = 0; kt < 2; ++kt) {
      const float* W = kt ? WH : WI;
#pragma unroll
      for (int j = 0; j < 8; ++j) {
        const float* src = W + (16 * j + c) * 32 + 8 * q;
        unsigned hu[8], lu[8];
#pragma unroll
        for (int e = 0; e < 8; ++e) {
          float w = src[e] * L2E;
          unsigned b = __float_as_uint(w);
          hu[e] = b & 0xffff0000u;
          float lo = w - __uint_as_float(hu[e]);
          lu[e] = __float_as_uint(lo) & 0xffff0000u;
        }
#pragma unroll
        for (int p = 0; p < 4; ++p) {
          bwh[kt][j][p] = (hu[2 * p] >> 16) | hu[2 * p + 1];
          bwl[kt][j][p] = (lu[2 * p] >> 16) | lu[2 * p + 1];
        }
      }
    }
  }
  float bv[8];
#pragma unroll
  for (int j = 0; j < 8; ++j)
    bv[j] = (bih[wv * 128 + 16 * j + c] + bhh[wv * 128 + 16 * j + c]) * L2E;

  float wa0 = 0.f, wa1 = 0.f;
  if (wv == 3) { wa0 = Wa[c] * L2E; wa1 = Wa[c + 16] * L2E; }

  // per-lane state: rows 4q+e, hidden cols c (cs0) and c+16 (cs1)
  float cs0[4], cs1[4], mr[4], sr[4], cx0[4], cx1[4];
#pragma unroll
  for (int e = 0; e < 4; ++e) {
    cs0[e] = 0.f; cs1[e] = 0.f; mr[e] = -1e30f; sr[e] = 0.f; cx0[e] = 0.f; cx1[e] = 0.f;
  }

  // embedding prefetch state (wave 0 only): em holds emb row slice for timestep t
  float4 em0 = make_float4(0.f, 0.f, 0.f, 0.f);
  float4 em1 = make_float4(0.f, 0.f, 0.f, 0.f);
  int idxn = 0;
  if (wv == 0) {
    int i0 = x[(rowbase + c) * TSEQ];
    em0 = *(const float4*)(emb + i0 * 32 + 8 * q);
    em1 = *(const float4*)(emb + i0 * 32 + 8 * q + 4);
  }

  __syncthreads();

  for (int s = 0; s < TSEQ + 3; ++s) {
    const int t = s - wv;
    const bool active = ((unsigned)t < (unsigned)TSEQ);
    const int rp = (s + 1) & 1;   // read parity (data written at s-1)
    const int wp = s & 1;         // write parity

    // issue next idx load early (wave 0)
    if (wv == 0 && t + 1 < TSEQ) idxn = x[(rowbase + c) * TSEQ + t + 1];

    unsigned aih[4], ail[4], ahh[4], ahl[4];
    if (active) {
      if (wv == 0) {
        // build A in-part from prefetched embedding regs (natural scale)
        float w[8] = {em0.x, em0.y, em0.z, em0.w, em1.x, em1.y, em1.z, em1.w};
        unsigned hu[8], lu[8];
#pragma unroll
        for (int e = 0; e < 8; ++e) {
          unsigned b = __float_as_uint(w[e]);
          hu[e] = b & 0xffff0000u;
          lu[e] = __float_as_uint(w[e] - __uint_as_float(hu[e])) & 0xffff0000u;
        }
#pragma unroll
        for (int p = 0; p < 4; ++p) {
          aih[p] = (hu[2 * p] >> 16) | hu[2 * p + 1];
          ail[p] = (lu[2 * p] >> 16) | lu[2 * p + 1];
        }
      } else {
        const unsigned* base = hbuf + (rp * 4 + (wv - 1)) * 512 + c * 32;
        const int s0 = (((2 * q)     ^ (c & 7)) << 2);
        const int s1 = (((2 * q + 1) ^ (c & 7)) << 2);
        uint4 p0 = *(const uint4*)(base + s0);
        uint4 p1 = *(const uint4*)(base + s1);
        aih[0] = (p0.x & 0xffffu) | (p0.y << 16);
        ail[0] = (p0.x >> 16)     | (p0.y & 0xffff0000u);
        aih[1] = (p0.z & 0xffffu) | (p0.w << 16);
        ail[1] = (p0.z >> 16)     | (p0.w & 0xffff0000u);
        aih[2] = (p1.x & 0xffffu) | (p1.y << 16);
        ail[2] = (p1.x >> 16)     | (p1.y & 0xffff0000u);
        aih[3] = (p1.z & 0xffffu) | (p1.w << 16);
        ail[3] = (p1.z >> 16)     | (p1.w & 0xffff0000u);
      }
      {
        // A h-part: own layer's h at t-1
        const unsigned* base = hbuf + (rp * 4 + wv) * 512 + c * 32;
        const int s0 = (((2 * q)     ^ (c & 7)) << 2);
        const int s1 = (((2 * q + 1) ^ (c & 7)) << 2);
        uint4 p0 = *(const uint4*)(base + s0);
        uint4 p1 = *(const uint4*)(base + s1);
        ahh[0] = (p0.x & 0xffffu) | (p0.y << 16);
        ahl[0] = (p0.x >> 16)     | (p0.y & 0xffff0000u);
        ahh[1] = (p0.z & 0xffffu) | (p0.w << 16);
        ahl[1] = (p0.z >> 16)     | (p0.w & 0xffff0000u);
        ahh[2] = (p1.x & 0xffffu) | (p1.y << 16);
        ahl[2] = (p1.x >> 16)     | (p1.y & 0xffff0000u);
        ahh[3] = (p1.z & 0xffffu) | (p1.w << 16);
        ahl[3] = (p1.z >> 16)     | (p1.w & 0xffff0000u);
      }

      f32x4 acc[8];
#pragma unroll
      for (int j = 0; j < 8; ++j) {
        f32x4 a; a[0] = bv[j]; a[1] = bv[j]; a[2] = bv[j]; a[3] = bv[j];
        acc[j] = a;
      }
      const short8 Aih = frag(aih), Ail = frag(ail);
      const short8 Ahh = frag(ahh), Ahl = frag(ahl);
#pragma unroll
      for (int j = 0; j < 8; ++j) {
        const short8 Bh0 = frag(bwh[0][j]), Bl0 = frag(bwl[0][j]);
        const short8 Bh1 = frag(bwh[1][j]), Bl1 = frag(bwl[1][j]);
        acc[j] = __builtin_amdgcn_mfma_f32_16x16x32_bf16(Aih, Bh0, acc[j], 0, 0, 0);
        acc[j] = __builtin_amdgcn_mfma_f32_16x16x32_bf16(Ail, Bh0, acc[j], 0, 0, 0);
        acc[j] = __builtin_amdgcn_mfma_f32_16x16x32_bf16(Aih, Bl0, acc[j], 0, 0, 0);
        acc[j] = __builtin_amdgcn_mfma_f32_16x16x32_bf16(Ahh, Bh1, acc[j], 0, 0, 0);
        acc[j] = __builtin_amdgcn_mfma_f32_16x16x32_bf16(Ahl, Bh1, acc[j], 0, 0, 0);
        acc[j] = __builtin_amdgcn_mfma_f32_16x16x32_bf16(Ahh, Bl1, acc[j], 0, 0, 0);
      }

      // consume idx, issue emb loads for t+1 (latency hides under gate math)
      if (wv == 0 && t + 1 < TSEQ) {
        em0 = *(const float4*)(emb + idxn * 32 + 8 * q);
        em1 = *(const float4*)(emb + idxn * 32 + 8 * q + 4);
      }

      // ---- gates (z' = z*log2e; tiles: i=0,1 f=2,3 g=4,5 o=6,7)
      float hv0[4], hv1[4];
#pragma unroll
      for (int e = 0; e < 4; ++e) {
        float si = sigm2(acc[0][e]);
        float sf = sigm2(acc[2][e]);
        float tg = tanh2(acc[4][e]);
        float so = sigm2(acc[6][e]);
        float cc = sf * cs0[e] + si * tg;
        cs0[e] = cc;
        hv0[e] = so * tanh2(cc * L2E);

        float si1 = sigm2(acc[1][e]);
        float sf1 = sigm2(acc[3][e]);
        float tg1 = tanh2(acc[5][e]);
        float so1 = sigm2(acc[7][e]);
        float cc1 = sf1 * cs1[e] + si1 * tg1;
        cs1[e] = cc1;
        hv1[e] = so1 * tanh2(cc1 * L2E);
      }

      // ---- write h (packed hi/lo) into swizzled LDS
      {
        unsigned* base = hbuf + (wp * 4 + wv) * 512;
#pragma unroll
        for (int e = 0; e < 4; ++e) {
          const int r  = 4 * q + e;
          const int rb = r * 32;
          const int o0 = ((((c)      >> 2) ^ (r & 7)) << 2) | (c & 3);
          const int o1 = ((((c + 16) >> 2) ^ (r & 7)) << 2) | (c & 3);
          base[rb + o0] = packhl(hv0[e]);
          base[rb + o1] = packhl(hv1[e]);
        }
      }

      // ---- online-softmax attention (wave 3; scores pre-scaled by log2e, ba cancels)
      if (wv == 3) {
        float p[4];
#pragma unroll
        for (int e = 0; e < 4; ++e) p[e] = hv0[e] * wa0 + hv1[e] * wa1;
#pragma unroll
        for (int mk = 1; mk <= 8; mk <<= 1) {
#pragma unroll
          for (int e = 0; e < 4; ++e) p[e] += __shfl_xor(p[e], mk, 64);
        }
#pragma unroll
        for (int e = 0; e < 4; ++e) {
          float mn = fmaxf(mr[e], p[e]);
          float sc = fexp2(mr[e] - mn);
          float pr = fexp2(p[e] - mn);
          sr[e]  = sr[e] * sc + pr;
          cx0[e] = cx0[e] * sc + pr * hv0[e];
          cx1[e] = cx1[e] * sc + pr * hv1[e];
          mr[e] = mn;
        }
      }
    }
    __syncthreads();
  }

  // ---- head (wave 3): context -> tanh MLP -> out
  float* cb = (float*)hbuf;   // reuse LDS as fp32 [16][33]
  if (wv == 3) {
#pragma unroll
    for (int e = 0; e < 4; ++e) {
      const int r = 4 * q + e;
      float inv = frcp(sr[e]);
      cb[r * 33 + c]      = cx0[e] * inv;
      cb[r * 33 + c + 16] = cx1[e] * inv;
    }
  }
  __syncthreads();
  if (wv != 3) return;

  float a0[4], a1[4];
  {
    float bb0 = b1[c], bb1 = b1[c + 16];
#pragma unroll
    for (int e = 0; e < 4; ++e) { a0[e] = bb0; a1[e] = bb1; }
    for (int j = 0; j < 32; ++j) {
      float w0 = W1[j * 32 + c];
      float w1 = W1[j * 32 + c + 16];
#pragma unroll
      for (int e = 0; e < 4; ++e) {
        float cr = cb[(4 * q + e) * 33 + j];
        a0[e] = fmaf(cr, w0, a0[e]);
        a1[e] = fmaf(cr, w1, a1[e]);
      }
    }
  }
  float o0[4], o1[4], o2[4];
  {
    float w20 = W2[c * 3 + 0], w21 = W2[c * 3 + 1], w22 = W2[c * 3 + 2];
    float w30 = W2[(c + 16) * 3 + 0], w31 = W2[(c + 16) * 3 + 1], w32 = W2[(c + 16) * 3 + 2];
#pragma unroll
    for (int e = 0; e < 4; ++e) {
      float h0 = tanh2(a0[e] * L2E);
      float h1 = tanh2(a1[e] * L2E);
      o0[e] = h0 * w20 + h1 * w30;
      o1[e] = h0 * w21 + h1 * w31;
      o2[e] = h0 * w22 + h1 * w32;
    }
  }
#pragma unroll
  for (int mk = 1; mk <= 8; mk <<= 1) {
#pragma unroll
    for (int e = 0; e < 4; ++e) {
      o0[e] += __shfl_xor(o0[e], mk, 64);
      o1[e] += __shfl_xor(o1[e], mk, 64);
      o2[e] += __shfl_xor(o2[e], mk, 64);
    }
  }
  if (c < 3) {
    float bb = b2[c];
#pragma unroll
    for (int e = 0; e < 4; ++e) {
      float v = (c == 0) ? o0[e] : ((c == 1) ? o1[e] : o2[e]);
      out[(rowbase + 4 * q + e) * 3 + c] = v + bb;
    }
  }
}

extern "C" void kernel_launch(void* const* d_in, const int* in_sizes, int n_in,
                              void* d_out, int out_size, void* d_ws, size_t ws_size,
                              hipStream_t stream) {
  const int*   x   = (const int*)d_in[0];
  const float* emb = (const float*)d_in[1];
  const float* Wih = (const float*)d_in[2];
  const float* Whh = (const float*)d_in[3];
  const float* bih = (const float*)d_in[4];
  const float* bhh = (const float*)d_in[5];
  const float* Wa  = (const float*)d_in[6];
  // d_in[7] = ba: softmax is shift-invariant, so ba cancels exactly
  const float* W1  = (const float*)d_in[8];
  const float* b1  = (const float*)d_in[9];
  const float* W2  = (const float*)d_in[10];
  const float* b2  = (const float*)d_in[11];
  float* out = (float*)d_out;

  lstm_fused<<<512, 256, 0, stream>>>(x, emb, Wih, Whh, bih, bhh, Wa, W1, b1, W2, b2, out);
}

// Round 2
// 268.883 us; speedup vs baseline: 1.0492x; 1.0492x over previous
//
#include <hip/hip_runtime.h>

#define TSEQ 111
#define L2E 1.44269504088896340736f
#define TWO_L2E 2.88539008177792680472f

using f32x4  = __attribute__((ext_vector_type(4))) float;
using short8 = __attribute__((ext_vector_type(8))) short;

union FragU { unsigned u[4]; uint4 v; short8 s; };

__device__ __forceinline__ short8 frag(const unsigned u[4]) {
  FragU f;
  f.u[0] = u[0]; f.u[1] = u[1]; f.u[2] = u[2]; f.u[3] = u[3];
  return f.s;
}

__device__ __forceinline__ float fexp2(float x) { return __builtin_amdgcn_exp2f(x); }
__device__ __forceinline__ float frcp(float x)  { return __builtin_amdgcn_rcpf(x); }
// tanh(z) given zs = z*log2(e)
__device__ __forceinline__ float tanh2(float zs) { return 1.f - 2.f * frcp(1.f + fexp2(zs + zs)); }

// pack fp32 -> (bf16 hi | bf16 lo) in one u32: element0 = hi, element1 = lo (as bf16x2)
__device__ __forceinline__ unsigned packhl(float h) {
  unsigned b  = __float_as_uint(h);
  unsigned hi = b & 0xffff0000u;
  float lo    = h - __uint_as_float(hi);
  return (hi >> 16) | (__float_as_uint(lo) & 0xffff0000u);
}
// round-to-nearest bf16, return as high-16 mask
__device__ __forceinline__ unsigned rnd_bf16_hi(float w) {
  unsigned u = __float_as_uint(w);
  u += 0x7fffu + ((u >> 16) & 1u);
  return u & 0xffff0000u;
}

// Block = 4 waves (one per LSTM layer), 16 batch rows/block; wave-level pipeline over t.
// MFMA 16x16x32 bf16 with K-interleaved (hi,lo) A and k-pair-duplicated bf16 B:
//   A slot k=2m -> hi(h[col0+m]), k=2m+1 -> lo(h[col0+m]); B slots 2m,2m+1 both = w_bf16[col0+m]
// => one MFMA = exact (hi+lo)*w_bf16 over 16 real columns; 2 MFMAs per 32-wide operand.
// Gate tiles j: i={0,1} f={2,3} g={4,5} o={6,7}; i/f/o folded by -log2e, g by +2*log2e.
__global__ __launch_bounds__(256, 2) void lstm_fused(
    const int* __restrict__ x, const float* __restrict__ emb,
    const float* __restrict__ Wih, const float* __restrict__ Whh,
    const float* __restrict__ bih, const float* __restrict__ bhh,
    const float* __restrict__ Wa, const float* __restrict__ W1,
    const float* __restrict__ b1, const float* __restrict__ W2,
    const float* __restrict__ b2, float* __restrict__ out)
{
  // [parity][layer][16 rows][32 cols] packed (hi|lo) u32, XOR-swizzled per 16B
  __shared__ unsigned hbuf[2 * 4 * 512];

  const int tid  = threadIdx.x;
  const int wv   = tid >> 6;     // layer id 0..3
  const int lane = tid & 63;
  const int c    = lane & 15;    // batch row (A) / gate col (B,C)
  const int q    = lane >> 4;    // k-quad / C-row-quad
  const int rowbase = blockIdx.x * 16;

  for (int i = tid; i < 2 * 4 * 512; i += 256) hbuf[i] = 0u;

  // ---- weights -> register-resident duplicated-bf16 B-fragments, sign/scale folded
  unsigned bw[2][2][8][4];   // [ih/hh][K-half][gate tile][frag regs]
#pragma unroll
  for (int kt = 0; kt < 2; ++kt) {
    const float* W = (kt ? Whh : Wih) + wv * 4096;
#pragma unroll
    for (int hf = 0; hf < 2; ++hf) {
#pragma unroll
      for (int j = 0; j < 8; ++j) {
        const float sj = (j == 4 || j == 5) ? TWO_L2E : -L2E;
        const float* src = W + (16 * j + c) * 32 + hf * 16 + 4 * q;
#pragma unroll
        for (int p = 0; p < 4; ++p) {
          unsigned hi = rnd_bf16_hi(src[p] * sj);
          bw[kt][hf][j][p] = (hi >> 16) | hi;   // same bf16 in both halves
        }
      }
    }
  }
  float bv[8];
#pragma unroll
  for (int j = 0; j < 8; ++j) {
    const float sj = (j == 4 || j == 5) ? TWO_L2E : -L2E;
    bv[j] = (bih[wv * 128 + 16 * j + c] + bhh[wv * 128 + 16 * j + c]) * sj;
  }

  float wa0 = 0.f, wa1 = 0.f;
  if (wv == 3) { wa0 = Wa[c] * L2E; wa1 = Wa[c + 16] * L2E; }

  // per-lane state: rows 4q+e, hidden cols c (…0) and c+16 (…1)
  float cs0[4], cs1[4], mr[4], sr[4], cx0[4], cx1[4];
#pragma unroll
  for (int e = 0; e < 4; ++e) {
    cs0[e] = 0.f; cs1[e] = 0.f; mr[e] = -1e30f; sr[e] = 0.f; cx0[e] = 0.f; cx1[e] = 0.f;
  }

  // wave-0 embedding prefetch: em = emb slices for current t; idx1 = row index for t+1
  float em0[4] = {0, 0, 0, 0}, em1[4] = {0, 0, 0, 0};
  int idx1 = 0;
  if (wv == 0) {
    int i0 = x[(rowbase + c) * TSEQ];
    float4 a = *(const float4*)(emb + i0 * 32 + 4 * q);
    float4 b = *(const float4*)(emb + i0 * 32 + 16 + 4 * q);
    em0[0] = a.x; em0[1] = a.y; em0[2] = a.z; em0[3] = a.w;
    em1[0] = b.x; em1[1] = b.y; em1[2] = b.z; em1[3] = b.w;
    idx1 = x[(rowbase + c) * TSEQ + 1];
  }

  __syncthreads();

  for (int s = 0; s < TSEQ + 3; ++s) {
    const int t = s - wv;
    const bool active = ((unsigned)t < (unsigned)TSEQ);
    const int rp = (s + 1) & 1;   // read parity
    const int wp = s & 1;         // write parity

    float nem0[4], nem1[4];
    bool havePrefetch = false;
    if (wv == 0 && active) {
      // issue next-timestep embedding + next-next idx loads FIRST (full superstep to cover)
      if (t + 1 < TSEQ) {
        float4 a = *(const float4*)(emb + idx1 * 32 + 4 * q);
        float4 b = *(const float4*)(emb + idx1 * 32 + 16 + 4 * q);
        nem0[0] = a.x; nem0[1] = a.y; nem0[2] = a.z; nem0[3] = a.w;
        nem1[0] = b.x; nem1[1] = b.y; nem1[2] = b.z; nem1[3] = b.w;
        havePrefetch = true;
      }
      if (t + 2 < TSEQ) idx1 = x[(rowbase + c) * TSEQ + t + 2];
    }

    if (active) {
      FragU fi1, fi2, fh1, fh2;
      const int s0 = ((q ^ (c & 7)) << 2);
      if (wv == 0) {
#pragma unroll
        for (int p = 0; p < 4; ++p) { fi1.u[p] = packhl(em0[p]); fi2.u[p] = packhl(em1[p]); }
      } else {
        const unsigned* bIn = hbuf + (rp * 4 + (wv - 1)) * 512 + c * 32;
        fi1.v = *(const uint4*)(bIn + s0);
        fi2.v = *(const uint4*)(bIn + (s0 ^ 16));
      }
      {
        const unsigned* bH = hbuf + (rp * 4 + wv) * 512 + c * 32;
        fh1.v = *(const uint4*)(bH + s0);
        fh2.v = *(const uint4*)(bH + (s0 ^ 16));
      }

      f32x4 acc[8];
#pragma unroll
      for (int j = 0; j < 8; ++j) {
        f32x4 a; a[0] = bv[j]; a[1] = bv[j]; a[2] = bv[j]; a[3] = bv[j];
        acc[j] = a;
      }
#pragma unroll
      for (int j = 0; j < 8; ++j) {
        acc[j] = __builtin_amdgcn_mfma_f32_16x16x32_bf16(fi1.s, frag(bw[0][0][j]), acc[j], 0, 0, 0);
        acc[j] = __builtin_amdgcn_mfma_f32_16x16x32_bf16(fi2.s, frag(bw[0][1][j]), acc[j], 0, 0, 0);
        acc[j] = __builtin_amdgcn_mfma_f32_16x16x32_bf16(fh1.s, frag(bw[1][0][j]), acc[j], 0, 0, 0);
        acc[j] = __builtin_amdgcn_mfma_f32_16x16x32_bf16(fh2.s, frag(bw[1][1][j]), acc[j], 0, 0, 0);
      }

      // ---- gates with shared reciprocals
      // acc i-tile = -zi*log2e ; f = -zf*log2e ; g = +2*zg*log2e ; o = -zo*log2e
      float hv0[4], hv1[4];
#pragma unroll
      for (int e = 0; e < 4; ++e) {
        {
          float a_ = fexp2(acc[0][e]);            // e^{-zi}
          float m_ = fexp2(acc[2][e]);            // e^{-zf}
          float b_ = fexp2(acc[4][e]);            // e^{2 zg}
          float p_ = fexp2(acc[6][e]);            // e^{-zo}
          float A1 = 1.f + a_, B1 = 1.f + b_, M1 = 1.f + m_;
          float P  = A1 * B1;
          float cn = (cs0[e] * P + (b_ - 1.f) * M1) * frcp(M1 * P);
          cs0[e] = cn;
          float qv = fexp2(fminf(cn * TWO_L2E, 80.f));  // e^{2c}
          hv0[e] = (qv - 1.f) * frcp((1.f + p_) * (1.f + qv));
        }
        {
          float a_ = fexp2(acc[1][e]);
          float m_ = fexp2(acc[3][e]);
          float b_ = fexp2(acc[5][e]);
          float p_ = fexp2(acc[7][e]);
          float A1 = 1.f + a_, B1 = 1.f + b_, M1 = 1.f + m_;
          float P  = A1 * B1;
          float cn = (cs1[e] * P + (b_ - 1.f) * M1) * frcp(M1 * P);
          cs1[e] = cn;
          float qv = fexp2(fminf(cn * TWO_L2E, 80.f));
          hv1[e] = (qv - 1.f) * frcp((1.f + p_) * (1.f + qv));
        }
      }

      // ---- write h (packed hi|lo) into swizzled LDS
      {
        unsigned* base = hbuf + (wp * 4 + wv) * 512;
#pragma unroll
        for (int e = 0; e < 4; ++e) {
          const int r  = 4 * q + e;
          const int rb = r * 32;
          const int o0 = ((((c)      >> 2) ^ (r & 7)) << 2) | (c & 3);
          const int o1 = ((((c + 16) >> 2) ^ (r & 7)) << 2) | (c & 3);
          base[rb + o0] = packhl(hv0[e]);
          base[rb + o1] = packhl(hv1[e]);
        }
      }

      // ---- online-softmax attention (wave 3; scores pre-scaled by log2e, ba cancels)
      if (wv == 3) {
        float p[4];
#pragma unroll
        for (int e = 0; e < 4; ++e) p[e] = hv0[e] * wa0 + hv1[e] * wa1;
#pragma unroll
        for (int mk = 1; mk <= 8; mk <<= 1) {
#pragma unroll
          for (int e = 0; e < 4; ++e) p[e] += __shfl_xor(p[e], mk, 64);
        }
#pragma unroll
        for (int e = 0; e < 4; ++e) {
          float mn = fmaxf(mr[e], p[e]);
          float sc = fexp2(mr[e] - mn);
          float pr = fexp2(p[e] - mn);
          sr[e]  = sr[e] * sc + pr;
          cx0[e] = cx0[e] * sc + pr * hv0[e];
          cx1[e] = cx1[e] * sc + pr * hv1[e];
          mr[e] = mn;
        }
      }

      if (wv == 0 && havePrefetch) {
#pragma unroll
        for (int p = 0; p < 4; ++p) { em0[p] = nem0[p]; em1[p] = nem1[p]; }
      }
    }
    __syncthreads();
  }

  // ---- head (wave 3): context -> tanh MLP -> out
  float* cb = (float*)hbuf;   // reuse LDS as fp32 [16][33]
  if (wv == 3) {
#pragma unroll
    for (int e = 0; e < 4; ++e) {
      const int r = 4 * q + e;
      float inv = frcp(sr[e]);
      cb[r * 33 + c]      = cx0[e] * inv;
      cb[r * 33 + c + 16] = cx1[e] * inv;
    }
  }
  __syncthreads();
  if (wv != 3) return;

  float a0[4], a1[4];
  {
    float bb0 = b1[c], bb1 = b1[c + 16];
#pragma unroll
    for (int e = 0; e < 4; ++e) { a0[e] = bb0; a1[e] = bb1; }
    for (int j = 0; j < 32; ++j) {
      float w0 = W1[j * 32 + c];
      float w1 = W1[j * 32 + c + 16];
#pragma unroll
      for (int e = 0; e < 4; ++e) {
        float cr = cb[(4 * q + e) * 33 + j];
        a0[e] = fmaf(cr, w0, a0[e]);
        a1[e] = fmaf(cr, w1, a1[e]);
      }
    }
  }
  float o0[4], o1[4], o2[4];
  {
    float w20 = W2[c * 3 + 0], w21 = W2[c * 3 + 1], w22 = W2[c * 3 + 2];
    float w30 = W2[(c + 16) * 3 + 0], w31 = W2[(c + 16) * 3 + 1], w32 = W2[(c + 16) * 3 + 2];
#pragma unroll
    for (int e = 0; e < 4; ++e) {
      float h0 = tanh2(a0[e] * L2E);
      float h1 = tanh2(a1[e] * L2E);
      o0[e] = h0 * w20 + h1 * w30;
      o1[e] = h0 * w21 + h1 * w31;
      o2[e] = h0 * w22 + h1 * w32;
    }
  }
#pragma unroll
  for (int mk = 1; mk <= 8; mk <<= 1) {
#pragma unroll
    for (int e = 0; e < 4; ++e) {
      o0[e] += __shfl_xor(o0[e], mk, 64);
      o1[e] += __shfl_xor(o1[e], mk, 64);
      o2[e] += __shfl_xor(o2[e], mk, 64);
    }
  }
  if (c < 3) {
    float bb = b2[c];
#pragma unroll
    for (int e = 0; e < 4; ++e) {
      float v = (c == 0) ? o0[e] : ((c == 1) ? o1[e] : o2[e]);
      out[(rowbase + 4 * q + e) * 3 + c] = v + bb;
    }
  }
}

extern "C" void kernel_launch(void* const* d_in, const int* in_sizes, int n_in,
                              void* d_out, int out_size, void* d_ws, size_t ws_size,
                              hipStream_t stream) {
  const int*   x   = (const int*)d_in[0];
  const float* emb = (const float*)d_in[1];
  const float* Wih = (const float*)d_in[2];
  const float* Whh = (const float*)d_in[3];
  const float* bih = (const float*)d_in[4];
  const float* bhh = (const float*)d_in[5];
  const float* Wa  = (const float*)d_in[6];
  // d_in[7] = ba: softmax is shift-invariant, so ba cancels exactly
  const float* W1  = (const float*)d_in[8];
  const float* b1  = (const float*)d_in[9];
  const float* W2  = (const float*)d_in[10];
  const float* b2  = (const float*)d_in[11];
  float* out = (float*)d_out;

  lstm_fused<<<512, 256, 0, stream>>>(x, emb, Wih, Whh, bih, bhh, Wa, W1, b1, W2, b2, out);
}

// Round 3
// 209.709 us; speedup vs baseline: 1.3453x; 1.2822x over previous
//
#include <hip/hip_runtime.h>

#define TSEQ 111
#define L2E 1.44269504088896340736f
#define TWO_L2E 2.88539008177792680472f

using f32x4  = __attribute__((ext_vector_type(4))) float;
using short8 = __attribute__((ext_vector_type(8))) short;

union FragU { unsigned u[4]; uint4 v; short8 s; };

__device__ __forceinline__ float fexp2(float x) { return __builtin_amdgcn_exp2f(x); }
__device__ __forceinline__ float frcp(float x)  { return __builtin_amdgcn_rcpf(x); }
// tanh(z) given zs = z*log2(e)
__device__ __forceinline__ float tanh2(float zs) { return 1.f - 2.f * frcp(1.f + fexp2(zs + zs)); }

// round-to-nearest bf16, value in LOW 16 bits of result
__device__ __forceinline__ unsigned rnd_bf16(float w) {
  unsigned u = __float_as_uint(w);
  return (u + 0x7fffu + ((u >> 16) & 1u)) >> 16;
}
__device__ __forceinline__ unsigned pack2(float a, float b) {
  return rnd_bf16(a) | (rnd_bf16(b) << 16);
}
// low halves of (u0,u1) -> u0.lo | u1.lo<<16   (v_perm_b32)
__device__ __forceinline__ unsigned permlo(unsigned u1, unsigned u0) {
  return __builtin_amdgcn_perm(u1, u0, 0x05040100u);
}

// Block = 8 waves = 4 layers x 2 hidden-halves, 16 batch rows/block.
// Wave (l,hf) computes gate tiles j = 2g+hf (g=i,f,g,o), cols hf*16..hf*16+15.
// hbuf slots: 0 = embedded input (written by L0 waves, one step ahead),
//             k = h of layer k-1. u32 cell per (row,col): bf16 value in low 16.
// 16B-chunk XOR swizzle within each 128B row: chunk CH stored at CH ^ (row&7).
// A-frag (16x32): lane(c=lane&15, q=lane>>4): row c, k = 8q+e.
// B-frag: col = lane&15 (gate within tile), k = 8q+e.
// C-frag: col = lane&15, row = 4q+e (m89-verified).
__global__ __launch_bounds__(512, 4) void lstm_fused(
    const int* __restrict__ x, const float* __restrict__ emb,
    const float* __restrict__ Wih, const float* __restrict__ Whh,
    const float* __restrict__ bih, const float* __restrict__ bhh,
    const float* __restrict__ Wa, const float* __restrict__ W1,
    const float* __restrict__ b1, const float* __restrict__ W2,
    const float* __restrict__ b2, float* __restrict__ out)
{
  __shared__ unsigned hbuf[2 * 5 * 512];   // [parity][slot][16 rows][32 cols]
  __shared__ float pbuf[2][2][16];         // [parity][half][row] partial scores

  const int tid  = threadIdx.x;
  const int wv2  = tid >> 6;       // 0..7
  const int l    = wv2 >> 1;       // layer 0..3
  const int hf   = wv2 & 1;        // hidden half
  const int lane = tid & 63;
  const int c    = lane & 15;
  const int q    = lane >> 4;
  const int cm7  = c & 7;
  const int rowbase = blockIdx.x * 16;
  const int xrow = (rowbase + c) * TSEQ;

  // ---- weights -> register-resident bf16 B-fragments (RTN), sign/scale folded
  FragU wihf[4], whhf[4];
#pragma unroll
  for (int g = 0; g < 4; ++g) {
    const float sj = (g == 2) ? TWO_L2E : -L2E;
    const int j = 2 * g + hf;
    const float* srcI = Wih + l * 4096 + (16 * j + c) * 32 + 8 * q;
    const float* srcH = Whh + l * 4096 + (16 * j + c) * 32 + 8 * q;
#pragma unroll
    for (int p = 0; p < 4; ++p) {
      wihf[g].u[p] = pack2(srcI[2 * p] * sj, srcI[2 * p + 1] * sj);
      whhf[g].u[p] = pack2(srcH[2 * p] * sj, srcH[2 * p + 1] * sj);
    }
  }
  float bv[4];
#pragma unroll
  for (int g = 0; g < 4; ++g) {
    const float sj = (g == 2) ? TWO_L2E : -L2E;
    const int j = 2 * g + hf;
    bv[g] = (bih[l * 128 + 16 * j + c] + bhh[l * 128 + 16 * j + c]) * sj;
  }
  const float wa = (l == 3) ? Wa[hf * 16 + c] * L2E : 0.f;

  // per-lane state: cell for rows 4q+e, col hf*16+c; attention state (l==3 only)
  float cs[4], mr[4], sr[4], cx[4], hp[4], ppv[4];
#pragma unroll
  for (int e = 0; e < 4; ++e) {
    cs[e] = 0.f; mr[e] = -1e30f; sr[e] = 0.f; cx[e] = 0.f; hp[e] = 0.f; ppv[e] = 0.f;
  }

  // ---- zero LDS, then stage emb(t=0) into parity-1 slot 0
  for (int i = tid; i < 2 * 5 * 512; i += 512) hbuf[i] = 0u;
  if (tid < 64) ((float*)pbuf)[tid] = 0.f;
  __syncthreads();

  int idx1 = 0;
  if (l == 0) {
    idx1 = x[xrow];
    const float* er = emb + idx1 * 32 + hf * 16 + 4 * q;
    float4 a = *(const float4*)er;
    *(uint4*)(hbuf + (1 * 5 + 0) * 512 + c * 32 + (((hf * 4 + q) ^ cm7) << 2)) =
        make_uint4(rnd_bf16(a.x), rnd_bf16(a.y), rnd_bf16(a.z), rnd_bf16(a.w));
    idx1 = x[xrow + 1];
  }
  __syncthreads();

  for (int s = 0; s < TSEQ + 4; ++s) {
    const int t = s - l;
    const bool active = ((unsigned)t < (unsigned)TSEQ);
    const int rp = (s + 1) & 1;   // read parity (written at s-1)
    const int wp = s & 1;         // write parity

    // ---- deferred online-softmax update for t3 = s-4 (layer-3 waves)
    if (l == 3 && s >= 4) {
#pragma unroll
      for (int e = 0; e < 4; ++e) {
        float pf = ppv[e] + pbuf[rp][1 - hf][4 * q + e];
        float mn = fmaxf(mr[e], pf);
        float sc = fexp2(mr[e] - mn);
        float pr = fexp2(pf - mn);
        sr[e] = sr[e] * sc + pr;
        cx[e] = cx[e] * sc + pr * hp[e];
        mr[e] = mn;
      }
    }

    // ---- L0 waves: stage emb(t+1) into slot 0 (wp), prefetch idx(t+2)
    if (l == 0 && active) {
      if (t + 1 < TSEQ) {
        const float* er = emb + idx1 * 32 + hf * 16 + 4 * q;
        float4 a = *(const float4*)er;
        *(uint4*)(hbuf + (wp * 5 + 0) * 512 + c * 32 + (((hf * 4 + q) ^ cm7) << 2)) =
            make_uint4(rnd_bf16(a.x), rnd_bf16(a.y), rnd_bf16(a.z), rnd_bf16(a.w));
      }
      if (t + 2 < TSEQ) idx1 = x[xrow + t + 2];
    }

    if (active) {
      // ---- A-fragments from LDS (input of layer l; own h at t-1)
      FragU fi, fh;
      {
        const unsigned* bi = hbuf + (rp * 5 + l) * 512 + c * 32;
        const int j0 = (((2 * q) ^ cm7) << 2);
        const int j1 = (((2 * q + 1) ^ cm7) << 2);
        uint4 p0 = *(const uint4*)(bi + j0);
        uint4 p1 = *(const uint4*)(bi + j1);
        fi.u[0] = permlo(p0.y, p0.x); fi.u[1] = permlo(p0.w, p0.z);
        fi.u[2] = permlo(p1.y, p1.x); fi.u[3] = permlo(p1.w, p1.z);
        const unsigned* bh = hbuf + (rp * 5 + l + 1) * 512 + c * 32;
        uint4 h0 = *(const uint4*)(bh + j0);
        uint4 h1 = *(const uint4*)(bh + j1);
        fh.u[0] = permlo(h0.y, h0.x); fh.u[1] = permlo(h0.w, h0.z);
        fh.u[2] = permlo(h1.y, h1.x); fh.u[3] = permlo(h1.w, h1.z);
      }

      f32x4 acc[4];
#pragma unroll
      for (int g = 0; g < 4; ++g) {
        f32x4 a; a[0] = bv[g]; a[1] = bv[g]; a[2] = bv[g]; a[3] = bv[g];
        acc[g] = a;
      }
#pragma unroll
      for (int g = 0; g < 4; ++g) {
        acc[g] = __builtin_amdgcn_mfma_f32_16x16x32_bf16(fi.s, wihf[g].s, acc[g], 0, 0, 0);
        acc[g] = __builtin_amdgcn_mfma_f32_16x16x32_bf16(fh.s, whhf[g].s, acc[g], 0, 0, 0);
      }

      // ---- gates: acc0=-zi*l2e acc1=-zf*l2e acc2=+2zg*l2e acc3=-zo*l2e
      float hv[4];
#pragma unroll
      for (int e = 0; e < 4; ++e) {
        float a_ = fexp2(acc[0][e]);
        float m_ = fexp2(acc[1][e]);
        float b_ = fexp2(acc[2][e]);
        float p_ = fexp2(acc[3][e]);
        float P  = (1.f + a_) * (1.f + b_);
        float M1 = 1.f + m_;
        float cn = (cs[e] * P + (b_ - 1.f) * M1) * frcp(M1 * P);
        cs[e] = cn;
        float qv = fexp2(fminf(cn * TWO_L2E, 80.f));
        hv[e] = (qv - 1.f) * frcp((1.f + p_) * (1.f + qv));
      }

      // ---- write h(t) as bf16 into swizzled slot l+1 (wp)
      {
        unsigned* ob = hbuf + (wp * 5 + l + 1) * 512;
        const int CL = hf * 16 + c;
#pragma unroll
        for (int e = 0; e < 4; ++e) {
          const int r = 4 * q + e;
          ob[r * 32 + ((((CL >> 2) ^ (r & 7)) << 2) | (CL & 3))] = rnd_bf16(hv[e]);
        }
      }

      // ---- layer-3: partial attention score, stash for deferred combine
      if (l == 3) {
        float pp[4];
#pragma unroll
        for (int e = 0; e < 4; ++e) pp[e] = hv[e] * wa;
#pragma unroll
        for (int mk = 1; mk <= 8; mk <<= 1) {
#pragma unroll
          for (int e = 0; e < 4; ++e) pp[e] += __shfl_xor(pp[e], mk, 64);
        }
#pragma unroll
        for (int e = 0; e < 4; ++e) {
          pbuf[wp][hf][4 * q + e] = pp[e];
          hp[e] = hv[e];
          ppv[e] = pp[e];
        }
      }
    }
    __syncthreads();
  }

  // ---- context -> LDS (fp32 [16][33])
  float* cb = (float*)hbuf;
  if (l == 3) {
#pragma unroll
    for (int e = 0; e < 4; ++e) {
      const int r = 4 * q + e;
      float inv = frcp(sr[e]);
      cb[r * 33 + hf * 16 + c] = cx[e] * inv;
    }
  }
  __syncthreads();
  if (wv2 != 6) return;

  // ---- head (single wave): tanh MLP -> out
  float a0[4], a1[4];
  {
    float bb0 = b1[c], bb1 = b1[c + 16];
#pragma unroll
    for (int e = 0; e < 4; ++e) { a0[e] = bb0; a1[e] = bb1; }
    for (int j = 0; j < 32; ++j) {
      float w0 = W1[j * 32 + c];
      float w1 = W1[j * 32 + c + 16];
#pragma unroll
      for (int e = 0; e < 4; ++e) {
        float cr = cb[(4 * q + e) * 33 + j];
        a0[e] = fmaf(cr, w0, a0[e]);
        a1[e] = fmaf(cr, w1, a1[e]);
      }
    }
  }
  float o0[4], o1[4], o2[4];
  {
    float w20 = W2[c * 3 + 0], w21 = W2[c * 3 + 1], w22 = W2[c * 3 + 2];
    float w30 = W2[(c + 16) * 3 + 0], w31 = W2[(c + 16) * 3 + 1], w32 = W2[(c + 16) * 3 + 2];
#pragma unroll
    for (int e = 0; e < 4; ++e) {
      float h0 = tanh2(a0[e] * L2E);
      float h1 = tanh2(a1[e] * L2E);
      o0[e] = h0 * w20 + h1 * w30;
      o1[e] = h0 * w21 + h1 * w31;
      o2[e] = h0 * w22 + h1 * w32;
    }
  }
#pragma unroll
  for (int mk = 1; mk <= 8; mk <<= 1) {
#pragma unroll
    for (int e = 0; e < 4; ++e) {
      o0[e] += __shfl_xor(o0[e], mk, 64);
      o1[e] += __shfl_xor(o1[e], mk, 64);
      o2[e] += __shfl_xor(o2[e], mk, 64);
    }
  }
  if (c < 3) {
    float bb = b2[c];
#pragma unroll
    for (int e = 0; e < 4; ++e) {
      float v = (c == 0) ? o0[e] : ((c == 1) ? o1[e] : o2[e]);
      out[(rowbase + 4 * q + e) * 3 + c] = v + bb;
    }
  }
}

extern "C" void kernel_launch(void* const* d_in, const int* in_sizes, int n_in,
                              void* d_out, int out_size, void* d_ws, size_t ws_size,
                              hipStream_t stream) {
  const int*   x   = (const int*)d_in[0];
  const float* emb = (const float*)d_in[1];
  const float* Wih = (const float*)d_in[2];
  const float* Whh = (const float*)d_in[3];
  const float* bih = (const float*)d_in[4];
  const float* bhh = (const float*)d_in[5];
  const float* Wa  = (const float*)d_in[6];
  // d_in[7] = ba: softmax is shift-invariant, so ba cancels exactly
  const float* W1  = (const float*)d_in[8];
  const float* b1  = (const float*)d_in[9];
  const float* W2  = (const float*)d_in[10];
  const float* b2  = (const float*)d_in[11];
  float* out = (float*)d_out;

  lstm_fused<<<512, 512, 0, stream>>>(x, emb, Wih, Whh, bih, bhh, Wa, W1, b1, W2, b2, out);
}

// Round 4
// 206.632 us; speedup vs baseline: 1.3653x; 1.0149x over previous
//
#include <hip/hip_runtime.h>

#define TSEQ 111
#define L2E 1.44269504088896340736f
#define TWO_L2E 2.88539008177792680472f

using f32x4  = __attribute__((ext_vector_type(4))) float;
using short8 = __attribute__((ext_vector_type(8))) short;

union FragU { unsigned u[4]; uint4 v; short8 s; };

__device__ __forceinline__ float fexp2(float x) { return __builtin_amdgcn_exp2f(x); }
__device__ __forceinline__ float frcp(float x)  { return __builtin_amdgcn_rcpf(x); }
// tanh(z) given zs = z*log2(e)
__device__ __forceinline__ float tanh2(float zs) { return 1.f - 2.f * frcp(1.f + fexp2(zs + zs)); }

// round-to-nearest bf16, value in LOW 16 bits
__device__ __forceinline__ unsigned rnd_bf16(float w) {
  unsigned u = __float_as_uint(w);
  return (u + 0x7fffu + ((u >> 16) & 1u)) >> 16;
}
__device__ __forceinline__ unsigned pack2(float a, float b) {
  return rnd_bf16(a) | (rnd_bf16(b) << 16);
}

// Block = 8 waves = 4 layers x 2 hidden-halves, 16 batch rows/block.
// Wave (l,hf) computes gate tiles j = 2g+hf (g=i,f,g,o), hidden cols hf*16..hf*16+15.
// hb slots (bf16 [16 rows][32 cols], row=64B, 16B chunks XOR-swizzled by g(row)=(row&3)^(row>>2)):
//   slot 0 = embedded input (staged by L0 waves one step ahead), slot k = h of layer k-1.
// A-frag (16x32): lane(c=lane&15,q=lane>>4) holds row c, k=8q..8q+7 -> ONE ds_read_b128.
// C-frag: col = lane&15, row = 4q+e.
// Attention (l=3): 3-stage pipeline: s: compute h(t) -> s+1: shuffle-reduce partial score,
// post to pbuf -> s+2: combine with partner partial, online-softmax update.
__global__ __launch_bounds__(512, 4) void lstm_fused(
    const int* __restrict__ x, const float* __restrict__ emb,
    const float* __restrict__ Wih, const float* __restrict__ Whh,
    const float* __restrict__ bih, const float* __restrict__ bhh,
    const float* __restrict__ Wa, const float* __restrict__ W1,
    const float* __restrict__ b1, const float* __restrict__ W2,
    const float* __restrict__ b2, float* __restrict__ out)
{
  __shared__ __align__(16) unsigned short hb[2 * 5 * 512];  // [parity][slot][16][32] bf16
  __shared__ float pbuf[2][2][16];                          // [parity][half][row]

  const int tid  = threadIdx.x;
  const int wv2  = tid >> 6;       // 0..7
  const int l    = wv2 >> 1;       // layer 0..3
  const int hf   = wv2 & 1;        // hidden half
  const int lane = tid & 63;
  const int c    = lane & 15;
  const int q    = lane >> 4;
  const int gc   = (c & 3) ^ (c >> 2);   // read-swizzle for row c
  const int rowbase = blockIdx.x * 16;
  const int xrow = (rowbase + c) * TSEQ;

  // lane-static LDS offsets (in shorts)
  const int rdOff = c * 32 + ((q ^ gc) << 3);          // A-frag read offset within a slot
  const int u     = hf * 16 + c;                        // owned hidden col
  const int uhi   = (u >> 3);                           // chunk of owned col
  const int ulo   = (u & 7);

  // ---- weights -> register-resident bf16 B-fragments (RTN), sign/scale folded
  FragU wihf[4], whhf[4];
#pragma unroll
  for (int g = 0; g < 4; ++g) {
    const float sj = (g == 2) ? TWO_L2E : -L2E;
    const int j = 2 * g + hf;
    const float* srcI = Wih + l * 4096 + (16 * j + c) * 32 + 8 * q;
    const float* srcH = Whh + l * 4096 + (16 * j + c) * 32 + 8 * q;
#pragma unroll
    for (int p = 0; p < 4; ++p) {
      wihf[g].u[p] = pack2(srcI[2 * p] * sj, srcI[2 * p + 1] * sj);
      whhf[g].u[p] = pack2(srcH[2 * p] * sj, srcH[2 * p + 1] * sj);
    }
  }
  float bv[4];
#pragma unroll
  for (int g = 0; g < 4; ++g) {
    const float sj = (g == 2) ? TWO_L2E : -L2E;
    const int j = 2 * g + hf;
    bv[g] = (bih[l * 128 + 16 * j + c] + bhh[l * 128 + 16 * j + c]) * sj;
  }
  const float wa = (l == 3) ? Wa[hf * 16 + c] * L2E : 0.f;

  // per-lane state
  float cs[4], mr[4], sr[4], cx[4];
  float h1[4], hp2[4], pp2[4];     // attention pipeline (l==3)
#pragma unroll
  for (int e = 0; e < 4; ++e) {
    cs[e] = 0.f; mr[e] = -1e30f; sr[e] = 0.f; cx[e] = 0.f;
    h1[e] = 0.f; hp2[e] = 0.f; pp2[e] = 0.f;
  }

  // ---- zero LDS
  for (int i = tid; i < 2 * 5 * 512 / 2; i += 512) ((unsigned*)hb)[i] = 0u;
  if (tid < 64) ((float*)pbuf)[tid] = 0.f;
  __syncthreads();

  // ---- L0 prologue: emb(0) -> slot0 parity1; embR = emb(1); idx2 = token(2)
  float4 embR = make_float4(0.f, 0.f, 0.f, 0.f);
  int idx2 = 0;
  const int embWrOff = c * 32 + ((((hf << 1) + (q >> 1)) ^ gc) << 3) + ((q & 1) << 2);
  if (l == 0) {
    int i0 = x[xrow];
    float4 a = *(const float4*)(emb + i0 * 32 + hf * 16 + 4 * q);
    *(uint2*)(hb + (1 * 5 + 0) * 512 + embWrOff) = make_uint2(pack2(a.x, a.y), pack2(a.z, a.w));
    int i1 = x[xrow + 1];
    embR = *(const float4*)(emb + i1 * 32 + hf * 16 + 4 * q);
    idx2 = x[xrow + 2];
  }
  __syncthreads();

  for (int s = 0; s < TSEQ + 5; ++s) {
    const int t = s - l;
    const bool active = ((unsigned)t < (unsigned)TSEQ);
    const int rp = (s + 1) & 1;   // read parity
    const int wp = s & 1;         // write parity

    // ---- wave3 P1: combine score(t-2) = s-5 with partner partial, softmax update
    if (l == 3 && s >= 5) {
#pragma unroll
      for (int e = 0; e < 4; ++e) {
        float pf = pp2[e] + pbuf[rp][1 - hf][4 * q + e];
        float mn = fmaxf(mr[e], pf);
        float sc = fexp2(mr[e] - mn);
        float pr = fexp2(pf - mn);
        sr[e] = sr[e] * sc + pr;
        cx[e] = cx[e] * sc + pr * hp2[e];
        mr[e] = mn;
      }
    }
    // ---- wave3 P2: shuffle-reduce score(t-1) = s-4, post partial
    if (l == 3 && s >= 4 && s <= TSEQ + 3) {
      float pp[4];
#pragma unroll
      for (int e = 0; e < 4; ++e) pp[e] = h1[e] * wa;
#pragma unroll
      for (int mk = 1; mk <= 8; mk <<= 1) {
#pragma unroll
        for (int e = 0; e < 4; ++e) pp[e] += __shfl_xor(pp[e], mk, 64);
      }
      if (c < 4) {
        float w = (c == 0) ? pp[0] : (c == 1) ? pp[1] : (c == 2) ? pp[2] : pp[3];
        pbuf[wp][hf][4 * q + c] = w;
      }
#pragma unroll
      for (int e = 0; e < 4; ++e) { pp2[e] = pp[e]; hp2[e] = h1[e]; }
    }

    // ---- L0: write staged emb(t+1) -> slot0[wp]; issue loads for t+2 / token t+3
    if (l == 0) {
      if (t + 1 < TSEQ)
        *(uint2*)(hb + (wp * 5 + 0) * 512 + embWrOff) =
            make_uint2(pack2(embR.x, embR.y), pack2(embR.z, embR.w));
      if (t + 2 < TSEQ) embR = *(const float4*)(emb + idx2 * 32 + hf * 16 + 4 * q);
      if (t + 3 < TSEQ) idx2 = x[xrow + t + 3];
    }

    if (active) {
      // ---- A-fragments: ONE ds_read_b128 each
      FragU fi, fh;
      fi.v = *(const uint4*)(hb + (rp * 5 + l) * 512 + rdOff);
      fh.v = *(const uint4*)(hb + (rp * 5 + l + 1) * 512 + rdOff);

      f32x4 acc[4];
#pragma unroll
      for (int g = 0; g < 4; ++g) {
        f32x4 a; a[0] = bv[g]; a[1] = bv[g]; a[2] = bv[g]; a[3] = bv[g];
        acc[g] = a;
      }
#pragma unroll
      for (int g = 0; g < 4; ++g) {
        acc[g] = __builtin_amdgcn_mfma_f32_16x16x32_bf16(fi.s, wihf[g].s, acc[g], 0, 0, 0);
        acc[g] = __builtin_amdgcn_mfma_f32_16x16x32_bf16(fh.s, whhf[g].s, acc[g], 0, 0, 0);
      }

      // ---- gates: acc0=-zi*l2e acc1=-zf*l2e acc2=+2zg*l2e acc3=-zo*l2e
      float hv[4];
#pragma unroll
      for (int e = 0; e < 4; ++e) {
        float a_ = fexp2(acc[0][e]);
        float m_ = fexp2(acc[1][e]);
        float b_ = fexp2(acc[2][e]);
        float p_ = fexp2(acc[3][e]);
        float P  = (1.f + a_) * (1.f + b_);
        float M1 = 1.f + m_;
        float cn = (cs[e] * P + (b_ - 1.f) * M1) * frcp(M1 * P);
        cs[e] = cn;
        float qv = fexp2(fminf(cn * TWO_L2E, 80.f));
        hv[e] = (qv - 1.f) * frcp((1.f + p_) * (1.f + qv));
      }

      // ---- write h(t) bf16 -> slot l+1 [wp]  (4x ds_write_b16, swizzle g(r)=e^q)
      {
        unsigned short* ob = hb + (wp * 5 + l + 1) * 512;
#pragma unroll
        for (int e = 0; e < 4; ++e) {
          const int r = 4 * q + e;
          ob[r * 32 + (((uhi ^ (e ^ q)) << 3) | ulo)] = (unsigned short)rnd_bf16(hv[e]);
        }
      }

      if (l == 3) {
#pragma unroll
        for (int e = 0; e < 4; ++e) h1[e] = hv[e];
      }
    }
    __syncthreads();
  }

  // ---- context -> LDS (fp32 [16][33])
  float* cb = (float*)hb;
  if (l == 3) {
#pragma unroll
    for (int e = 0; e < 4; ++e) {
      const int r = 4 * q + e;
      float inv = frcp(sr[e]);
      cb[r * 33 + hf * 16 + c] = cx[e] * inv;
    }
  }
  __syncthreads();
  if (wv2 != 6) return;

  // ---- head (single wave): tanh MLP -> out
  float a0[4], a1[4];
  {
    float bb0 = b1[c], bb1 = b1[c + 16];
#pragma unroll
    for (int e = 0; e < 4; ++e) { a0[e] = bb0; a1[e] = bb1; }
    for (int j = 0; j < 32; ++j) {
      float w0 = W1[j * 32 + c];
      float w1 = W1[j * 32 + c + 16];
#pragma unroll
      for (int e = 0; e < 4; ++e) {
        float cr = cb[(4 * q + e) * 33 + j];
        a0[e] = fmaf(cr, w0, a0[e]);
        a1[e] = fmaf(cr, w1, a1[e]);
      }
    }
  }
  float o0[4], o1[4], o2[4];
  {
    float w20 = W2[c * 3 + 0], w21 = W2[c * 3 + 1], w22 = W2[c * 3 + 2];
    float w30 = W2[(c + 16) * 3 + 0], w31 = W2[(c + 16) * 3 + 1], w32 = W2[(c + 16) * 3 + 2];
#pragma unroll
    for (int e = 0; e < 4; ++e) {
      float h0 = tanh2(a0[e] * L2E);
      float h1_ = tanh2(a1[e] * L2E);
      o0[e] = h0 * w20 + h1_ * w30;
      o1[e] = h0 * w21 + h1_ * w31;
      o2[e] = h0 * w22 + h1_ * w32;
    }
  }
#pragma unroll
  for (int mk = 1; mk <= 8; mk <<= 1) {
#pragma unroll
    for (int e = 0; e < 4; ++e) {
      o0[e] += __shfl_xor(o0[e], mk, 64);
      o1[e] += __shfl_xor(o1[e], mk, 64);
      o2[e] += __shfl_xor(o2[e], mk, 64);
    }
  }
  if (c < 3) {
    float bb = b2[c];
#pragma unroll
    for (int e = 0; e < 4; ++e) {
      float v = (c == 0) ? o0[e] : ((c == 1) ? o1[e] : o2[e]);
      out[(rowbase + 4 * q + e) * 3 + c] = v + bb;
    }
  }
}

extern "C" void kernel_launch(void* const* d_in, const int* in_sizes, int n_in,
                              void* d_out, int out_size, void* d_ws, size_t ws_size,
                              hipStream_t stream) {
  const int*   x   = (const int*)d_in[0];
  const float* emb = (const float*)d_in[1];
  const float* Wih = (const float*)d_in[2];
  const float* Whh = (const float*)d_in[3];
  const float* bih = (const float*)d_in[4];
  const float* bhh = (const float*)d_in[5];
  const float* Wa  = (const float*)d_in[6];
  // d_in[7] = ba: softmax is shift-invariant, so ba cancels exactly
  const float* W1  = (const float*)d_in[8];
  const float* b1  = (const float*)d_in[9];
  const float* W2  = (const float*)d_in[10];
  const float* b2  = (const float*)d_in[11];
  float* out = (float*)d_out;

  lstm_fused<<<512, 512, 0, stream>>>(x, emb, Wih, Whh, bih, bhh, Wa, W1, b1, W2, b2, out);
}

// Round 5
// 176.677 us; speedup vs baseline: 1.5968x; 1.1695x over previous
//
#include <hip/hip_runtime.h>

#define TSEQ 111
#define L2E 1.44269504088896340736f
#define TWO_L2E 2.88539008177792680472f

using f32x4  = __attribute__((ext_vector_type(4))) float;
using short8 = __attribute__((ext_vector_type(8))) short;

union FragU { unsigned u[4]; uint4 v; short8 s; };

__device__ __forceinline__ float fexp2(float x) { return __builtin_amdgcn_exp2f(x); }
__device__ __forceinline__ float frcp(float x)  { return __builtin_amdgcn_rcpf(x); }
// tanh(z) given zs = z*log2(e)
__device__ __forceinline__ float tanh2(float zs) { return 1.f - 2.f * frcp(1.f + fexp2(zs + zs)); }

// round-to-nearest-even bf16, value in LOW 16 bits (used in weight prep, once)
__device__ __forceinline__ unsigned rnd_bf16(float w) {
  unsigned u = __float_as_uint(w);
  return (u + 0x7fffu + ((u >> 16) & 1u)) >> 16;
}
// packed f32->bf16x2 in ONE instruction: [bf16(a) | bf16(b)<<16]
__device__ __forceinline__ unsigned cvtpk(float a, float b) {
  unsigned r;
  asm("v_cvt_pk_bf16_f32 %0, %1, %2" : "=v"(r) : "v"(a), "v"(b));
  return r;
}

// Block = 8 waves = 4 layers x 2 hidden-halves, 16 batch rows/block.
// Wave (l,hf) computes gate tiles j = 2g+hf (g=i,f,g,o), hidden cols hf*16..hf*16+15.
// hb slots (bf16 [16 rows][32 cols], row=64B, 16B chunks XOR-swizzled by g(row)=(row&3)^(row>>2)):
//   slot 0 = embedded input (staged by L0 waves one step ahead), slot k = h of layer k-1.
// A-frag (16x32): lane(c=lane&15,q=lane>>4) holds row c, k=8q..8q+7 -> ONE ds_read_b128.
// C-frag: col = lane&15, row = 4q+e.
// Attention (l=3): score(t-1) via extra MFMA on fh (h3(t-1)) against Wa-col B-frag
// (hi/lo split), broadcast per 16-lane group with ds_swizzle, online-softmax update.
// Both l3 waves duplicate this tiny work -> zero cross-wave exchange.
// Main-loop barrier = lgkmcnt-only (no vmcnt drain): global prefetches stay in flight.
__global__ __launch_bounds__(512, 4) void lstm_fused(
    const int* __restrict__ x, const float* __restrict__ emb,
    const float* __restrict__ Wih, const float* __restrict__ Whh,
    const float* __restrict__ bih, const float* __restrict__ bhh,
    const float* __restrict__ Wa, const float* __restrict__ W1,
    const float* __restrict__ b1, const float* __restrict__ W2,
    const float* __restrict__ b2, float* __restrict__ out)
{
  __shared__ __align__(16) unsigned short hb[2 * 5 * 512];  // [parity][slot][16][32] bf16

  const int tid  = threadIdx.x;
  const int wv2  = tid >> 6;       // 0..7
  const int l    = wv2 >> 1;       // layer 0..3
  const int hf   = wv2 & 1;        // hidden half
  const int lane = tid & 63;
  const int c    = lane & 15;
  const int q    = lane >> 4;
  const int gc   = (c & 3) ^ (c >> 2);   // read-swizzle for row c
  const int rowbase = blockIdx.x * 16;
  const int xrow = (rowbase + c) * TSEQ;

  // lane-static LDS offsets (in shorts)
  const int rdOff = c * 32 + ((q ^ gc) << 3);           // A-frag read offset within a slot
  const int u     = hf * 16 + c;                         // owned hidden col
  const int uhi   = (u >> 3);
  const int ulo   = (u & 7);

  // ---- weights -> register-resident bf16 B-fragments (RTN), sign/scale folded
  FragU wihf[4], whhf[4];
#pragma unroll
  for (int g = 0; g < 4; ++g) {
    const float sj = (g == 2) ? TWO_L2E : -L2E;
    const int j = 2 * g + hf;
    const float* srcI = Wih + l * 4096 + (16 * j + c) * 32 + 8 * q;
    const float* srcH = Whh + l * 4096 + (16 * j + c) * 32 + 8 * q;
#pragma unroll
    for (int p = 0; p < 4; ++p) {
      wihf[g].u[p] = rnd_bf16(srcI[2 * p] * sj) | (rnd_bf16(srcI[2 * p + 1] * sj) << 16);
      whhf[g].u[p] = rnd_bf16(srcH[2 * p] * sj) | (rnd_bf16(srcH[2 * p + 1] * sj) << 16);
    }
  }
  // biases as f32x4 C-operands (elides per-superstep acc-init copies)
  f32x4 bvv[4];
#pragma unroll
  for (int g = 0; g < 4; ++g) {
    const float sj = (g == 2) ? TWO_L2E : -L2E;
    const int j = 2 * g + hf;
    float b = (bih[l * 128 + 16 * j + c] + bhh[l * 128 + 16 * j + c]) * sj;
    bvv[g][0] = b; bvv[g][1] = b; bvv[g][2] = b; bvv[g][3] = b;
  }

  // ---- Wa -> B-frag (col 0 only), hi/lo split, scaled by log2e (l==3 waves)
  FragU wafh, wafl;
#pragma unroll
  for (int p = 0; p < 4; ++p) { wafh.u[p] = 0u; wafl.u[p] = 0u; }
  if (l == 3 && c == 0) {
#pragma unroll
    for (int p = 0; p < 4; ++p) {
      const int k0 = 8 * q + 2 * p;
      float w0 = Wa[k0] * L2E, w1 = Wa[k0 + 1] * L2E;
      unsigned h0 = rnd_bf16(w0), h1b = rnd_bf16(w1);
      wafh.u[p] = h0 | (h1b << 16);
      float l0 = w0 - __uint_as_float(h0 << 16);
      float l1 = w1 - __uint_as_float(h1b << 16);
      wafl.u[p] = rnd_bf16(l0) | (rnd_bf16(l1) << 16);
    }
  }

  // per-lane state
  float cs[4], mr[4], sr[4], cx[4], h1[4];
#pragma unroll
  for (int e = 0; e < 4; ++e) {
    cs[e] = 0.f; mr[e] = -1e30f; sr[e] = 0.f; cx[e] = 0.f; h1[e] = 0.f;
  }

  // ---- zero LDS
  for (int i = tid; i < 2 * 5 * 512 / 2; i += 512) ((unsigned*)hb)[i] = 0u;
  __syncthreads();

  // ---- L0 prologue: emb(0) -> slot0 parity1; embR = emb(1); idx2 = token(2)
  float4 embR = make_float4(0.f, 0.f, 0.f, 0.f);
  int idx2 = 0;
  const int embWrOff = c * 32 + ((((hf << 1) + (q >> 1)) ^ gc) << 3) + ((q & 1) << 2);
  if (l == 0) {
    int i0 = x[xrow];
    float4 a = *(const float4*)(emb + i0 * 32 + hf * 16 + 4 * q);
    *(uint2*)(hb + (1 * 5 + 0) * 512 + embWrOff) = make_uint2(cvtpk(a.x, a.y), cvtpk(a.z, a.w));
    int i1 = x[xrow + 1];
    embR = *(const float4*)(emb + i1 * 32 + hf * 16 + 4 * q);
    idx2 = x[xrow + 2];
  }
  __syncthreads();

  for (int s = 0; s < TSEQ + 4; ++s) {
    const int t = s - l;
    const bool active = ((unsigned)t < (unsigned)TSEQ);
    const int rp = (s + 1) & 1;   // read parity
    const int wp = s & 1;         // write parity

    // ---- L0: write staged emb(t+1) -> slot0[wp]; issue loads for t+2 / token t+3
    if (l == 0) {
      if (t + 1 < TSEQ)
        *(uint2*)(hb + (wp * 5 + 0) * 512 + embWrOff) =
            make_uint2(cvtpk(embR.x, embR.y), cvtpk(embR.z, embR.w));
      if (t + 2 < TSEQ) embR = *(const float4*)(emb + idx2 * 32 + hf * 16 + 4 * q);
      if (t + 3 < TSEQ) idx2 = x[xrow + t + 3];
    }

    // ---- A-fragment reads
    const bool rdF = active || (l == 3 && s == TSEQ + 3);
    FragU fi, fh;
    if (active) fi.v = *(const uint4*)(hb + (rp * 5 + l) * 512 + rdOff);
    if (rdF)    fh.v = *(const uint4*)(hb + (rp * 5 + l + 1) * 512 + rdOff);

    // ---- gate MFMAs (bias pre-loaded via C operand)
    f32x4 acc[4];
    if (active) {
#pragma unroll
      for (int g = 0; g < 4; ++g) {
        acc[g] = __builtin_amdgcn_mfma_f32_16x16x32_bf16(fi.s, wihf[g].s, bvv[g], 0, 0, 0);
        acc[g] = __builtin_amdgcn_mfma_f32_16x16x32_bf16(fh.s, whhf[g].s, acc[g], 0, 0, 0);
      }
    }

    // ---- l3: score(t-1) via MFMA on fh = h3(t-1); online-softmax update (uses old h1)
    if (l == 3 && s >= 4) {
      f32x4 sacc = __builtin_amdgcn_mfma_f32_16x16x32_bf16(
          fh.s, wafh.s, (f32x4){0.f, 0.f, 0.f, 0.f}, 0, 0, 0);
      sacc = __builtin_amdgcn_mfma_f32_16x16x32_bf16(fh.s, wafl.s, sacc, 0, 0, 0);
      float pf[4];
#pragma unroll
      for (int e = 0; e < 4; ++e)
        pf[e] = __int_as_float(
            __builtin_amdgcn_ds_swizzle(__float_as_int(sacc[e]), 0x0010));  // bcast lane 16q
#pragma unroll
      for (int e = 0; e < 4; ++e) {
        float mn = fmaxf(mr[e], pf[e]);
        float sc = fexp2(mr[e] - mn);
        float pr = fexp2(pf[e] - mn);
        sr[e] = sr[e] * sc + pr;
        cx[e] = cx[e] * sc + pr * h1[e];
        mr[e] = mn;
      }
    }

    if (active) {
      // ---- gates: acc0=-zi*l2e acc1=-zf*l2e acc2=+2zg*l2e acc3=-zo*l2e
      float hv[4];
#pragma unroll
      for (int e = 0; e < 4; ++e) {
        float a_ = fexp2(acc[0][e]);
        float m_ = fexp2(acc[1][e]);
        float b_ = fexp2(acc[2][e]);
        float p_ = fexp2(acc[3][e]);
        float P  = (1.f + a_) * (1.f + b_);
        float M1 = 1.f + m_;
        float cn = (cs[e] * P + (b_ - 1.f) * M1) * frcp(M1 * P);
        cs[e] = cn;
        float qv = fexp2(fminf(cn * TWO_L2E, 80.f));
        hv[e] = (qv - 1.f) * frcp((1.f + p_) * (1.f + qv));
      }

      // ---- write h(t) bf16 -> slot l+1 [wp]  (cvt_pk packing, 4x ds_write_b16)
      {
        unsigned short* ob = hb + (wp * 5 + l + 1) * 512;
        unsigned u01 = cvtpk(hv[0], hv[1]);
        unsigned u23 = cvtpk(hv[2], hv[3]);
        const int r0 = 4 * q;
        ob[(r0 + 0) * 32 + (((uhi ^ (0 ^ q)) << 3) | ulo)] = (unsigned short)(u01 & 0xffffu);
        ob[(r0 + 1) * 32 + (((uhi ^ (1 ^ q)) << 3) | ulo)] = (unsigned short)(u01 >> 16);
        ob[(r0 + 2) * 32 + (((uhi ^ (2 ^ q)) << 3) | ulo)] = (unsigned short)(u23 & 0xffffu);
        ob[(r0 + 3) * 32 + (((uhi ^ (3 ^ q)) << 3) | ulo)] = (unsigned short)(u23 >> 16);
      }

      if (l == 3) {
#pragma unroll
        for (int e = 0; e < 4; ++e) h1[e] = hv[e];
      }
    }

    // lgkm-only barrier: LDS traffic synced; global prefetches stay in flight
    asm volatile("s_waitcnt lgkmcnt(0)\n\ts_barrier" ::: "memory");
  }

  __syncthreads();

  // ---- context -> LDS (fp32 [16][33])
  float* cb = (float*)hb;
  if (l == 3) {
#pragma unroll
    for (int e = 0; e < 4; ++e) {
      const int r = 4 * q + e;
      float inv = frcp(sr[e]);
      cb[r * 33 + hf * 16 + c] = cx[e] * inv;
    }
  }
  __syncthreads();
  if (wv2 != 6) return;

  // ---- head (single wave): tanh MLP -> out
  float a0[4], a1[4];
  {
    float bb0 = b1[c], bb1 = b1[c + 16];
#pragma unroll
    for (int e = 0; e < 4; ++e) { a0[e] = bb0; a1[e] = bb1; }
    for (int j = 0; j < 32; ++j) {
      float w0 = W1[j * 32 + c];
      float w1 = W1[j * 32 + c + 16];
#pragma unroll
      for (int e = 0; e < 4; ++e) {
        float cr = cb[(4 * q + e) * 33 + j];
        a0[e] = fmaf(cr, w0, a0[e]);
        a1[e] = fmaf(cr, w1, a1[e]);
      }
    }
  }
  float o0[4], o1[4], o2[4];
  {
    float w20 = W2[c * 3 + 0], w21 = W2[c * 3 + 1], w22 = W2[c * 3 + 2];
    float w30 = W2[(c + 16) * 3 + 0], w31 = W2[(c + 16) * 3 + 1], w32 = W2[(c + 16) * 3 + 2];
#pragma unroll
    for (int e = 0; e < 4; ++e) {
      float h0 = tanh2(a0[e] * L2E);
      float hB = tanh2(a1[e] * L2E);
      o0[e] = h0 * w20 + hB * w30;
      o1[e] = h0 * w21 + hB * w31;
      o2[e] = h0 * w22 + hB * w32;
    }
  }
#pragma unroll
  for (int mk = 1; mk <= 8; mk <<= 1) {
#pragma unroll
    for (int e = 0; e < 4; ++e) {
      o0[e] += __shfl_xor(o0[e], mk, 64);
      o1[e] += __shfl_xor(o1[e], mk, 64);
      o2[e] += __shfl_xor(o2[e], mk, 64);
    }
  }
  if (c < 3) {
    float bb = b2[c];
#pragma unroll
    for (int e = 0; e < 4; ++e) {
      float v = (c == 0) ? o0[e] : ((c == 1) ? o1[e] : o2[e]);
      out[(rowbase + 4 * q + e) * 3 + c] = v + bb;
    }
  }
}

extern "C" void kernel_launch(void* const* d_in, const int* in_sizes, int n_in,
                              void* d_out, int out_size, void* d_ws, size_t ws_size,
                              hipStream_t stream) {
  const int*   x   = (const int*)d_in[0];
  const float* emb = (const float*)d_in[1];
  const float* Wih = (const float*)d_in[2];
  const float* Whh = (const float*)d_in[3];
  const float* bih = (const float*)d_in[4];
  const float* bhh = (const float*)d_in[5];
  const float* Wa  = (const float*)d_in[6];
  // d_in[7] = ba: softmax is shift-invariant, so ba cancels exactly
  const float* W1  = (const float*)d_in[8];
  const float* b1  = (const float*)d_in[9];
  const float* W2  = (const float*)d_in[10];
  const float* b2  = (const float*)d_in[11];
  float* out = (float*)d_out;

  lstm_fused<<<512, 512, 0, stream>>>(x, emb, Wih, Whh, bih, bhh, Wa, W1, b1, W2, b2, out);
}

// Round 6
// 167.453 us; speedup vs baseline: 1.6847x; 1.0551x over previous
//
#include <hip/hip_runtime.h>

#define TSEQ 111
#define L2E 1.44269504088896340736f
#define TWO_L2E 2.88539008177792680472f

using f32x4  = __attribute__((ext_vector_type(4))) float;
using short8 = __attribute__((ext_vector_type(8))) short;

union FragU { unsigned u[4]; uint4 v; short8 s; };

__device__ __forceinline__ float fexp2(float x) { return __builtin_amdgcn_exp2f(x); }
__device__ __forceinline__ float frcp(float x)  { return __builtin_amdgcn_rcpf(x); }
// tanh(z) given zs = z*log2(e)
__device__ __forceinline__ float tanh2(float zs) { return 1.f - 2.f * frcp(1.f + fexp2(zs + zs)); }

// round-to-nearest-even bf16, value in LOW 16 bits
__device__ __forceinline__ unsigned rnd_bf16(float w) {
  unsigned u = __float_as_uint(w);
  return (u + 0x7fffu + ((u >> 16) & 1u)) >> 16;
}
// packed f32->bf16x2 in ONE instruction: [bf16(a) | bf16(b)<<16]
__device__ __forceinline__ unsigned cvtpk(float a, float b) {
  unsigned r;
  asm("v_cvt_pk_bf16_f32 %0, %1, %2" : "=v"(r) : "v"(a), "v"(b));
  return r;
}

// Block = 8 waves = 4 layers x 2 hidden-halves, 16 batch rows/block.
// Wave (l,hf): gate tiles j = 2g+hf (g=i,f,g,o), hidden cols hf*16..hf*16+15.
// hb slots (bf16 [16 rows][32 cols], 64B rows, 16B chunks XOR-swizzled by g(row)=(row&3)^(row>>2)):
//   slot 0 = embedded input (staged by ALL waves, 2 rows each, one step ahead),
//   slot k = h of layer k-1. A/B-frag: lane(c,q): row/col c, k=8q..8q+7 -> ONE ds_read_b128.
// C-frag: col = lane&15, row = 4q+e.
// Attention on the l=1 wave pair (zero cross-lane): score(t-1) = mfma(A=Wa replicated
// over rows, B=h3(t-1) as B-frag) -> every elem of lane (c,q) = score(batch row c).
// Per-lane scalar online softmax; context cx in B-frag layout, split 4 cols per hf wave.
// Main-loop barrier = lgkmcnt-only: global prefetches stay in flight across it.
__global__ __launch_bounds__(512, 4) void lstm_fused(
    const int* __restrict__ x, const float* __restrict__ emb,
    const float* __restrict__ Wih, const float* __restrict__ Whh,
    const float* __restrict__ bih, const float* __restrict__ bhh,
    const float* __restrict__ Wa, const float* __restrict__ W1,
    const float* __restrict__ b1, const float* __restrict__ W2,
    const float* __restrict__ b2, float* __restrict__ out)
{
  __shared__ __align__(16) unsigned short hb[2 * 5 * 512];  // [parity][slot][16][32] bf16

  const int tid  = threadIdx.x;
  const int wvu  = __builtin_amdgcn_readfirstlane(tid) >> 6;  // wave id 0..7 (SGPR)
  const int l    = wvu >> 1;       // layer 0..3
  const int hf   = wvu & 1;        // hidden half
  const int lane = tid & 63;
  const int c    = lane & 15;
  const int q    = lane >> 4;
  const int gcc  = (c & 3) ^ (c >> 2);   // chunk swizzle for row c
  const int rowbase = blockIdx.x * 16;

  // lane-static LDS offsets (in shorts)
  const int rdOff = c * 32 + ((q ^ gcc) << 3);   // A/B-frag read offset within a slot
  const int u     = hf * 16 + c;                  // owned hidden col (gate path)
  const int uhi   = (u >> 3);
  const int ulo   = (u & 7);

  // emb staging mapping: each wave stages rows {2*wvu, 2*wvu+1}, cols 0..31
  const int srow  = 2 * wvu + (lane >> 5);
  const int scol  = lane & 31;
  const int sgc   = (srow & 3) ^ (srow >> 2);
  const int sOff  = srow * 32 + ((((scol >> 3) ^ sgc)) << 3) + (scol & 7);
  const int sxrow = (rowbase + srow) * TSEQ;

  // ---- weights -> register-resident bf16 B-fragments (RTN), sign/scale folded
  FragU wihf[4], whhf[4];
#pragma unroll
  for (int g = 0; g < 4; ++g) {
    const float sj = (g == 2) ? TWO_L2E : -L2E;
    const int j = 2 * g + hf;
    const float* srcI = Wih + l * 4096 + (16 * j + c) * 32 + 8 * q;
    const float* srcH = Whh + l * 4096 + (16 * j + c) * 32 + 8 * q;
#pragma unroll
    for (int p = 0; p < 4; ++p) {
      wihf[g].u[p] = rnd_bf16(srcI[2 * p] * sj) | (rnd_bf16(srcI[2 * p + 1] * sj) << 16);
      whhf[g].u[p] = rnd_bf16(srcH[2 * p] * sj) | (rnd_bf16(srcH[2 * p + 1] * sj) << 16);
    }
  }
  // biases as f32x4 C-operands
  f32x4 bvv[4];
#pragma unroll
  for (int g = 0; g < 4; ++g) {
    const float sj = (g == 2) ? TWO_L2E : -L2E;
    const int j = 2 * g + hf;
    float b = (bih[l * 128 + 16 * j + c] + bhh[l * 128 + 16 * j + c]) * sj;
    bvv[g][0] = b; bvv[g][1] = b; bvv[g][2] = b; bvv[g][3] = b;
  }

  // ---- Wa as A-frag replicated over rows (l==1 waves), hi/lo split, scaled by log2e
  FragU wahA, walA;
#pragma unroll
  for (int p = 0; p < 4; ++p) { wahA.u[p] = 0u; walA.u[p] = 0u; }
  if (l == 1) {
#pragma unroll
    for (int p = 0; p < 4; ++p) {
      const int k0 = 8 * q + 2 * p;
      float w0 = Wa[k0] * L2E, w1 = Wa[k0 + 1] * L2E;
      unsigned h0 = rnd_bf16(w0), h1b = rnd_bf16(w1);
      wahA.u[p] = h0 | (h1b << 16);
      float l0 = w0 - __uint_as_float(h0 << 16);
      float l1 = w1 - __uint_as_float(h1b << 16);
      walA.u[p] = rnd_bf16(l0) | (rnd_bf16(l1) << 16);
    }
  }

  // per-lane state: cell (rows 4q+e, col u); attention (l==1): row c, cols 8q+4hf..+3
  float cs[4];
#pragma unroll
  for (int e = 0; e < 4; ++e) cs[e] = 0.f;
  float mr = -1e30f, sr = 0.f, cx[4];
#pragma unroll
  for (int e = 0; e < 4; ++e) cx[e] = 0.f;

  // ---- zero LDS
  for (int i = tid; i < 2 * 5 * 512 / 2; i += 512) ((unsigned*)hb)[i] = 0u;
  __syncthreads();

  // ---- prologue staging (all waves): emb(0) -> slot0 parity1; embv = emb(1); idxn = x(2)
  {
    int i0 = x[sxrow];
    float e0 = emb[i0 * 32 + scol];
    hb[(1 * 5 + 0) * 512 + sOff] = (unsigned short)rnd_bf16(e0);
  }
  float embv = emb[x[sxrow + 1] * 32 + scol];
  int idxn = x[sxrow + 2];
  __syncthreads();

#pragma unroll 2
  for (int s = 0; s < TSEQ + 4; ++s) {
    const int t = s - l;
    const bool active = ((unsigned)t < (unsigned)TSEQ);
    const int rp = (s + 1) & 1;   // read parity
    const int wp = s & 1;         // write parity

    // ---- staging (all waves, symmetric): write emb(s+1), load emb(s+2), idx(s+3)
    if (s + 1 < TSEQ) hb[(wp * 5 + 0) * 512 + sOff] = (unsigned short)rnd_bf16(embv);
    if (s + 2 < TSEQ) embv = emb[idxn * 32 + scol];
    if (s + 3 < TSEQ) idxn = x[sxrow + s + 3];

    // ---- A-fragment reads
    FragU fi, fh, f3;
    if (active) {
      fi.v = *(const uint4*)(hb + (rp * 5 + l) * 512 + rdOff);
      fh.v = *(const uint4*)(hb + (rp * 5 + l + 1) * 512 + rdOff);
    }
    const bool doAtt = (l == 1) && (s >= 4);
    if (doAtt) f3.v = *(const uint4*)(hb + (rp * 5 + 4) * 512 + rdOff);

    if (active) {
      // ---- gate MFMAs (bias pre-loaded via C operand)
      f32x4 acc[4];
#pragma unroll
      for (int g = 0; g < 4; ++g) {
        acc[g] = __builtin_amdgcn_mfma_f32_16x16x32_bf16(fi.s, wihf[g].s, bvv[g], 0, 0, 0);
        acc[g] = __builtin_amdgcn_mfma_f32_16x16x32_bf16(fh.s, whhf[g].s, acc[g], 0, 0, 0);
      }

      // ---- gates: acc0=-zi*l2e acc1=-zf*l2e acc2=+2zg*l2e acc3=-zo*l2e
      float hv[4];
#pragma unroll
      for (int e = 0; e < 4; ++e) {
        float a_ = fexp2(acc[0][e]);
        float m_ = fexp2(acc[1][e]);
        float b_ = fexp2(acc[2][e]);
        float p_ = fexp2(acc[3][e]);
        float P  = (1.f + a_) * (1.f + b_);
        float M1 = 1.f + m_;
        float cn = (cs[e] * P + (b_ - 1.f) * M1) * frcp(M1 * P);
        cs[e] = cn;
        float qv = fexp2(fminf(cn * TWO_L2E, 80.f));
        hv[e] = (qv - 1.f) * frcp((1.f + p_) * (1.f + qv));
      }

      // ---- write h(t) bf16 -> slot l+1 [wp]
      {
        unsigned short* ob = hb + (wp * 5 + l + 1) * 512;
        unsigned u01 = cvtpk(hv[0], hv[1]);
        unsigned u23 = cvtpk(hv[2], hv[3]);
        const int r0 = 4 * q;
        ob[(r0 + 0) * 32 + (((uhi ^ (0 ^ q)) << 3) | ulo)] = (unsigned short)(u01 & 0xffffu);
        ob[(r0 + 1) * 32 + (((uhi ^ (1 ^ q)) << 3) | ulo)] = (unsigned short)(u01 >> 16);
        ob[(r0 + 2) * 32 + (((uhi ^ (2 ^ q)) << 3) | ulo)] = (unsigned short)(u23 & 0xffffu);
        ob[(r0 + 3) * 32 + (((uhi ^ (3 ^ q)) << 3) | ulo)] = (unsigned short)(u23 >> 16);
      }
    }

    // ---- attention (l=1 pair): score via replicated-A MFMA; per-lane online softmax
    if (doAtt) {
      f32x4 z = {0.f, 0.f, 0.f, 0.f};
      f32x4 sacc = __builtin_amdgcn_mfma_f32_16x16x32_bf16(wahA.s, f3.s, z, 0, 0, 0);
      sacc = __builtin_amdgcn_mfma_f32_16x16x32_bf16(walA.s, f3.s, sacc, 0, 0, 0);
      float pf = sacc[0];                    // score(batch row c), all elems equal
      float mn = fmaxf(mr, pf);
      float sc = fexp2(mr - mn);
      float pr = fexp2(pf - mn);
      sr = sr * sc + pr;
      // this wave accumulates cols 8q + 4*hf .. +3 (elems 2*hf*2.. of f3)
#pragma unroll
      for (int p = 0; p < 2; ++p) {
        unsigned w = f3.u[2 * hf + p];
        float vlo = __uint_as_float(w << 16);
        float vhi = __uint_as_float(w & 0xffff0000u);
        cx[2 * p]     = cx[2 * p]     * sc + pr * vlo;
        cx[2 * p + 1] = cx[2 * p + 1] * sc + pr * vhi;
      }
      mr = mn;
    }

    // lgkm-only barrier: LDS synced; global prefetches stay in flight
    asm volatile("s_waitcnt lgkmcnt(0)\n\ts_barrier" ::: "memory");
  }

  __syncthreads();

  // ---- context -> LDS (fp32 [16][33]); l=1 waves own it: row c, cols 8q+4hf+e
  float* cb = (float*)hb;
  if (l == 1) {
    float inv = frcp(sr);
#pragma unroll
    for (int e = 0; e < 4; ++e)
      cb[c * 33 + 8 * q + 4 * hf + e] = cx[e] * inv;
  }
  __syncthreads();
  if (wvu != 6) return;

  // ---- head (single wave): tanh MLP -> out
  float a0[4], a1[4];
  {
    float bb0 = b1[c], bb1 = b1[c + 16];
#pragma unroll
    for (int e = 0; e < 4; ++e) { a0[e] = bb0; a1[e] = bb1; }
    for (int j = 0; j < 32; ++j) {
      float w0 = W1[j * 32 + c];
      float w1 = W1[j * 32 + c + 16];
#pragma unroll
      for (int e = 0; e < 4; ++e) {
        float cr = cb[(4 * q + e) * 33 + j];
        a0[e] = fmaf(cr, w0, a0[e]);
        a1[e] = fmaf(cr, w1, a1[e]);
      }
    }
  }
  float o0[4], o1[4], o2[4];
  {
    float w20 = W2[c * 3 + 0], w21 = W2[c * 3 + 1], w22 = W2[c * 3 + 2];
    float w30 = W2[(c + 16) * 3 + 0], w31 = W2[(c + 16) * 3 + 1], w32 = W2[(c + 16) * 3 + 2];
#pragma unroll
    for (int e = 0; e < 4; ++e) {
      float h0 = tanh2(a0[e] * L2E);
      float hB = tanh2(a1[e] * L2E);
      o0[e] = h0 * w20 + hB * w30;
      o1[e] = h0 * w21 + hB * w31;
      o2[e] = h0 * w22 + hB * w32;
    }
  }
#pragma unroll
  for (int mk = 1; mk <= 8; mk <<= 1) {
#pragma unroll
    for (int e = 0; e < 4; ++e) {
      o0[e] += __shfl_xor(o0[e], mk, 64);
      o1[e] += __shfl_xor(o1[e], mk, 64);
      o2[e] += __shfl_xor(o2[e], mk, 64);
    }
  }
  if (c < 3) {
    float bb = b2[c];
#pragma unroll
    for (int e = 0; e < 4; ++e) {
      float v = (c == 0) ? o0[e] : ((c == 1) ? o1[e] : o2[e]);
      out[(rowbase + 4 * q + e) * 3 + c] = v + bb;
    }
  }
}

extern "C" void kernel_launch(void* const* d_in, const int* in_sizes, int n_in,
                              void* d_out, int out_size, void* d_ws, size_t ws_size,
                              hipStream_t stream) {
  const int*   x   = (const int*)d_in[0];
  const float* emb = (const float*)d_in[1];
  const float* Wih = (const float*)d_in[2];
  const float* Whh = (const float*)d_in[3];
  const float* bih = (const float*)d_in[4];
  const float* bhh = (const float*)d_in[5];
  const float* Wa  = (const float*)d_in[6];
  // d_in[7] = ba: softmax is shift-invariant, so ba cancels exactly
  const float* W1  = (const float*)d_in[8];
  const float* b1  = (const float*)d_in[9];
  const float* W2  = (const float*)d_in[10];
  const float* b2  = (const float*)d_in[11];
  float* out = (float*)d_out;

  lstm_fused<<<512, 512, 0, stream>>>(x, emb, Wih, Whh, bih, bhh, Wa, W1, b1, W2, b2, out);
}

// Round 7
// 165.401 us; speedup vs baseline: 1.7056x; 1.0124x over previous
//
#include <hip/hip_runtime.h>

#define TSEQ 111
#define L2E 1.44269504088896340736f
#define TWO_L2E 2.88539008177792680472f

using f32x4  = __attribute__((ext_vector_type(4))) float;
using f32x2  = __attribute__((ext_vector_type(2))) float;
using short8 = __attribute__((ext_vector_type(8))) short;

union FragU { unsigned u[4]; uint4 v; short8 s; };

__device__ __forceinline__ float fexp2(float x) { return __builtin_amdgcn_exp2f(x); }
__device__ __forceinline__ float frcp(float x)  { return __builtin_amdgcn_rcpf(x); }
// tanh(z) given zs = z*log2(e)
__device__ __forceinline__ float tanh2(float zs) { return 1.f - 2.f * frcp(1.f + fexp2(zs + zs)); }
__device__ __forceinline__ f32x2 exp2v(f32x2 x) { f32x2 r; r[0] = fexp2(x[0]); r[1] = fexp2(x[1]); return r; }
__device__ __forceinline__ f32x2 rcpv(f32x2 x)  { f32x2 r; r[0] = frcp(x[0]); r[1] = frcp(x[1]); return r; }

// round-to-nearest-even bf16, value in LOW 16 bits
__device__ __forceinline__ unsigned rnd_bf16(float w) {
  unsigned u = __float_as_uint(w);
  return (u + 0x7fffu + ((u >> 16) & 1u)) >> 16;
}
// packed f32->bf16x2 in ONE instruction: [bf16(a) | bf16(b)<<16]
__device__ __forceinline__ unsigned cvtpk(float a, float b) {
  unsigned r;
  asm("v_cvt_pk_bf16_f32 %0, %1, %2" : "=v"(r) : "v"(a), "v"(b));
  return r;
}

// Block = 8 waves = 4 layers x 2 hidden-halves, 16 batch rows/block.
// Wave (l,hf): gate tiles j = 2g+hf (g=i,f,g,o), hidden cols hf*16..hf*16+15.
// hb slots (bf16 [16 rows][32 cols], 64B rows, 16B chunks XOR-swizzled by g(row)=(row&3)^(row>>2)):
//   slot k = h of layer k (k=0..3). Layer-0 input (embeddings) goes DIRECTLY into
//   l0 waves' A-frag registers from global memory (one timestep ahead) - no LDS staging.
// A/B-frag: lane(c,q): row/col c, k=8q..8q+7 -> ONE ds_read_b128. C-frag: col c, row 4q+e.
// Attention on l=3 pair, reusing fh (= h3(t-1), exactly the frag attention needs):
// score = mfma(A=Wa replicated rows, B=fh) -> every elem = score(batch row c);
// per-lane scalar online softmax; cx cols split 4/lane-elem by hf. Zero cross-lane ops.
// Gate math in packed f32 (f32x2 -> v_pk_*_f32). Main-loop barrier = lgkmcnt-only.
__global__ __launch_bounds__(512, 4) void lstm_fused(
    const int* __restrict__ x, const float* __restrict__ emb,
    const float* __restrict__ Wih, const float* __restrict__ Whh,
    const float* __restrict__ bih, const float* __restrict__ bhh,
    const float* __restrict__ Wa, const float* __restrict__ W1,
    const float* __restrict__ b1, const float* __restrict__ W2,
    const float* __restrict__ b2, float* __restrict__ out)
{
  __shared__ __align__(16) unsigned short hb[2 * 4 * 512];  // [parity][slot][16][32] bf16

  const int tid  = threadIdx.x;
  const int wvu  = __builtin_amdgcn_readfirstlane(tid) >> 6;  // wave id 0..7 (SGPR)
  const int l    = wvu >> 1;       // layer 0..3
  const int hf   = wvu & 1;        // hidden half
  const int lane = tid & 63;
  const int c    = lane & 15;
  const int q    = lane >> 4;
  const int gcc  = (c & 3) ^ (c >> 2);   // chunk swizzle for row c
  const int rowbase = blockIdx.x * 16;
  const int xrow = (rowbase + c) * TSEQ;

  // lane-static LDS offsets (in shorts)
  const int rdOff = c * 32 + ((q ^ gcc) << 3);   // A/B-frag read offset within a slot
  const int u     = hf * 16 + c;                  // owned hidden col (gate path)
  const int uhi   = (u >> 3);
  const int ulo   = (u & 7);

  // ---- weights -> register-resident bf16 B-fragments (RTN), sign/scale folded
  FragU wihf[4], whhf[4];
#pragma unroll
  for (int g = 0; g < 4; ++g) {
    const float sj = (g == 2) ? TWO_L2E : -L2E;
    const int j = 2 * g + hf;
    const float* srcI = Wih + l * 4096 + (16 * j + c) * 32 + 8 * q;
    const float* srcH = Whh + l * 4096 + (16 * j + c) * 32 + 8 * q;
#pragma unroll
    for (int p = 0; p < 4; ++p) {
      wihf[g].u[p] = rnd_bf16(srcI[2 * p] * sj) | (rnd_bf16(srcI[2 * p + 1] * sj) << 16);
      whhf[g].u[p] = rnd_bf16(srcH[2 * p] * sj) | (rnd_bf16(srcH[2 * p + 1] * sj) << 16);
    }
  }
  // biases as f32x4 C-operands
  f32x4 bvv[4];
#pragma unroll
  for (int g = 0; g < 4; ++g) {
    const float sj = (g == 2) ? TWO_L2E : -L2E;
    const int j = 2 * g + hf;
    float b = (bih[l * 128 + 16 * j + c] + bhh[l * 128 + 16 * j + c]) * sj;
    bvv[g][0] = b; bvv[g][1] = b; bvv[g][2] = b; bvv[g][3] = b;
  }

  // ---- Wa as A-frag replicated over rows (l==3 waves), hi/lo split, scaled by log2e
  FragU wahA, walA;
#pragma unroll
  for (int p = 0; p < 4; ++p) { wahA.u[p] = 0u; walA.u[p] = 0u; }
  if (l == 3) {
#pragma unroll
    for (int p = 0; p < 4; ++p) {
      const int k0 = 8 * q + 2 * p;
      float w0 = Wa[k0] * L2E, w1 = Wa[k0 + 1] * L2E;
      unsigned h0 = rnd_bf16(w0), h1b = rnd_bf16(w1);
      wahA.u[p] = h0 | (h1b << 16);
      float l0v = w0 - __uint_as_float(h0 << 16);
      float l1v = w1 - __uint_as_float(h1b << 16);
      walA.u[p] = rnd_bf16(l0v) | (rnd_bf16(l1v) << 16);
    }
  }

  // per-lane state: cell pairs; attention (l==3): row c, cols 8q+4hf..+3
  f32x2 cs2[2];
  cs2[0] = (f32x2){0.f, 0.f}; cs2[1] = (f32x2){0.f, 0.f};
  float mr = -1e30f, sr = 0.f, cx[4];
#pragma unroll
  for (int e = 0; e < 4; ++e) cx[e] = 0.f;

  // ---- zero LDS
  for (int i = tid; i < 2 * 4 * 512 / 2; i += 512) ((unsigned*)hb)[i] = 0u;

  // ---- l0 prologue: emb(0) -> regs; idxn = token(1)
  float4 emA = make_float4(0.f, 0.f, 0.f, 0.f), emB = emA;
  int idxn = 0;
  if (l == 0) {
    int i0 = x[xrow];
    emA = *(const float4*)(emb + i0 * 32 + 8 * q);
    emB = *(const float4*)(emb + i0 * 32 + 8 * q + 4);
    idxn = x[xrow + 1];
  }
  __syncthreads();

#pragma unroll 2
  for (int s = 0; s < TSEQ + 4; ++s) {
    const int t = s - l;
    const bool active = ((unsigned)t < (unsigned)TSEQ);
    const int rp = (s + 1) & 1;   // read parity
    const int wp = s & 1;         // write parity
    const bool doAtt = (l == 3) && (s >= 4);

    // ---- A-fragment acquire
    FragU fi, fh;
    __builtin_amdgcn_s_setprio(1);
    if (active) {
      if (l == 0) {
        // build fi from prefetched emb regs; then issue loads for t+1
        fi.u[0] = cvtpk(emA.x, emA.y); fi.u[1] = cvtpk(emA.z, emA.w);
        fi.u[2] = cvtpk(emB.x, emB.y); fi.u[3] = cvtpk(emB.z, emB.w);
        if (t + 1 < TSEQ) {
          emA = *(const float4*)(emb + idxn * 32 + 8 * q);
          emB = *(const float4*)(emb + idxn * 32 + 8 * q + 4);
        }
        if (t + 2 < TSEQ) idxn = x[xrow + t + 2];
      } else {
        fi.v = *(const uint4*)(hb + (rp * 4 + (l - 1)) * 512 + rdOff);
      }
    }
    if (active || doAtt)
      fh.v = *(const uint4*)(hb + (rp * 4 + l) * 512 + rdOff);

    // ---- gate MFMAs (bias pre-loaded via C operand)
    f32x4 acc[4];
    if (active) {
#pragma unroll
      for (int g = 0; g < 4; ++g) {
        acc[g] = __builtin_amdgcn_mfma_f32_16x16x32_bf16(fi.s, wihf[g].s, bvv[g], 0, 0, 0);
        acc[g] = __builtin_amdgcn_mfma_f32_16x16x32_bf16(fh.s, whhf[g].s, acc[g], 0, 0, 0);
      }
    }
    // ---- attention score MFMAs (l=3, reuses fh = h3(t-1))
    f32x4 sacc;
    if (doAtt) {
      f32x4 z = {0.f, 0.f, 0.f, 0.f};
      sacc = __builtin_amdgcn_mfma_f32_16x16x32_bf16(wahA.s, fh.s, z, 0, 0, 0);
      sacc = __builtin_amdgcn_mfma_f32_16x16x32_bf16(walA.s, fh.s, sacc, 0, 0, 0);
    }
    __builtin_amdgcn_s_setprio(0);

    if (active) {
      // ---- gates (packed f32): acc0=-zi*l2e acc1=-zf*l2e acc2=+2zg*l2e acc3=-zo*l2e
      float hv[4];
      const f32x2 one = {1.f, 1.f};
      const f32x2 tl2 = {TWO_L2E, TWO_L2E};
#pragma unroll
      for (int pr2 = 0; pr2 < 2; ++pr2) {
        const int e0 = 2 * pr2;
        f32x2 va; va[0] = acc[0][e0]; va[1] = acc[0][e0 + 1];
        f32x2 vm; vm[0] = acc[1][e0]; vm[1] = acc[1][e0 + 1];
        f32x2 vb; vb[0] = acc[2][e0]; vb[1] = acc[2][e0 + 1];
        f32x2 vp; vp[0] = acc[3][e0]; vp[1] = acc[3][e0 + 1];
        f32x2 ea = exp2v(va), em_ = exp2v(vm), eb = exp2v(vb), ep = exp2v(vp);
        f32x2 P  = (one + ea) * (one + eb);
        f32x2 M1 = one + em_;
        f32x2 num = cs2[pr2] * P + (eb - one) * M1;
        f32x2 cn = num * rcpv(M1 * P);
        cs2[pr2] = cn;
        f32x2 qa = cn * tl2;
        qa[0] = fminf(qa[0], 80.f); qa[1] = fminf(qa[1], 80.f);
        f32x2 qv = exp2v(qa);
        f32x2 hvv = (qv - one) * rcpv((one + ep) * (one + qv));
        hv[e0] = hvv[0]; hv[e0 + 1] = hvv[1];
      }

      // ---- write h(t) bf16 -> slot l [wp]
      {
        unsigned short* ob = hb + (wp * 4 + l) * 512;
        unsigned u01 = cvtpk(hv[0], hv[1]);
        unsigned u23 = cvtpk(hv[2], hv[3]);
        const int r0 = 4 * q;
        ob[(r0 + 0) * 32 + (((uhi ^ (0 ^ q)) << 3) | ulo)] = (unsigned short)(u01 & 0xffffu);
        ob[(r0 + 1) * 32 + (((uhi ^ (1 ^ q)) << 3) | ulo)] = (unsigned short)(u01 >> 16);
        ob[(r0 + 2) * 32 + (((uhi ^ (2 ^ q)) << 3) | ulo)] = (unsigned short)(u23 & 0xffffu);
        ob[(r0 + 3) * 32 + (((uhi ^ (3 ^ q)) << 3) | ulo)] = (unsigned short)(u23 >> 16);
      }
    }

    // ---- attention online-softmax update (scalar per lane; score(row c) in sacc[0])
    if (doAtt) {
      float pf = sacc[0];
      float mn = fmaxf(mr, pf);
      float sc = fexp2(mr - mn);
      float pr = fexp2(pf - mn);
      sr = sr * sc + pr;
#pragma unroll
      for (int p = 0; p < 2; ++p) {
        unsigned w = fh.u[2 * hf + p];
        float vlo = __uint_as_float(w << 16);
        float vhi = __uint_as_float(w & 0xffff0000u);
        cx[2 * p]     = cx[2 * p]     * sc + pr * vlo;
        cx[2 * p + 1] = cx[2 * p + 1] * sc + pr * vhi;
      }
      mr = mn;
    }

    // lgkm-only barrier: LDS synced; global prefetches stay in flight
    asm volatile("s_waitcnt lgkmcnt(0)\n\ts_barrier" ::: "memory");
  }

  __syncthreads();

  // ---- context -> LDS (fp32 [16][33]); l=3 waves own it: row c, cols 8q+4hf+e
  float* cb = (float*)hb;
  if (l == 3) {
    float inv = frcp(sr);
#pragma unroll
    for (int e = 0; e < 4; ++e)
      cb[c * 33 + 8 * q + 4 * hf + e] = cx[e] * inv;
  }
  __syncthreads();
  if (wvu != 6) return;

  // ---- head (single wave): tanh MLP -> out
  float a0[4], a1[4];
  {
    float bb0 = b1[c], bb1 = b1[c + 16];
#pragma unroll
    for (int e = 0; e < 4; ++e) { a0[e] = bb0; a1[e] = bb1; }
    for (int j = 0; j < 32; ++j) {
      float w0 = W1[j * 32 + c];
      float w1 = W1[j * 32 + c + 16];
#pragma unroll
      for (int e = 0; e < 4; ++e) {
        float cr = cb[(4 * q + e) * 33 + j];
        a0[e] = fmaf(cr, w0, a0[e]);
        a1[e] = fmaf(cr, w1, a1[e]);
      }
    }
  }
  float o0[4], o1[4], o2[4];
  {
    float w20 = W2[c * 3 + 0], w21 = W2[c * 3 + 1], w22 = W2[c * 3 + 2];
    float w30 = W2[(c + 16) * 3 + 0], w31 = W2[(c + 16) * 3 + 1], w32 = W2[(c + 16) * 3 + 2];
#pragma unroll
    for (int e = 0; e < 4; ++e) {
      float h0 = tanh2(a0[e] * L2E);
      float hB = tanh2(a1[e] * L2E);
      o0[e] = h0 * w20 + hB * w30;
      o1[e] = h0 * w21 + hB * w31;
      o2[e] = h0 * w22 + hB * w32;
    }
  }
#pragma unroll
  for (int mk = 1; mk <= 8; mk <<= 1) {
#pragma unroll
    for (int e = 0; e < 4; ++e) {
      o0[e] += __shfl_xor(o0[e], mk, 64);
      o1[e] += __shfl_xor(o1[e], mk, 64);
      o2[e] += __shfl_xor(o2[e], mk, 64);
    }
  }
  if (c < 3) {
    float bb = b2[c];
#pragma unroll
    for (int e = 0; e < 4; ++e) {
      float v = (c == 0) ? o0[e] : ((c == 1) ? o1[e] : o2[e]);
      out[(rowbase + 4 * q + e) * 3 + c] = v + bb;
    }
  }
}

extern "C" void kernel_launch(void* const* d_in, const int* in_sizes, int n_in,
                              void* d_out, int out_size, void* d_ws, size_t ws_size,
                              hipStream_t stream) {
  const int*   x   = (const int*)d_in[0];
  const float* emb = (const float*)d_in[1];
  const float* Wih = (const float*)d_in[2];
  const float* Whh = (const float*)d_in[3];
  const float* bih = (const float*)d_in[4];
  const float* bhh = (const float*)d_in[5];
  const float* Wa  = (const float*)d_in[6];
  // d_in[7] = ba: softmax is shift-invariant, so ba cancels exactly
  const float* W1  = (const float*)d_in[8];
  const float* b1  = (const float*)d_in[9];
  const float* W2  = (const float*)d_in[10];
  const float* b2  = (const float*)d_in[11];
  float* out = (float*)d_out;

  lstm_fused<<<512, 512, 0, stream>>>(x, emb, Wih, Whh, bih, bhh, Wa, W1, b1, W2, b2, out);
}

// Round 8
// 159.757 us; speedup vs baseline: 1.7659x; 1.0353x over previous
//
#include <hip/hip_runtime.h>

#define TSEQ 111
#define L2E 1.44269504088896340736f
#define TWO_L2E 2.88539008177792680472f

using f32x4  = __attribute__((ext_vector_type(4))) float;
using f32x2  = __attribute__((ext_vector_type(2))) float;
using short8 = __attribute__((ext_vector_type(8))) short;

union FragU { unsigned u[4]; uint4 v; short8 s; };

__device__ __forceinline__ float fexp2(float x) { return __builtin_amdgcn_exp2f(x); }
__device__ __forceinline__ float frcp(float x)  { return __builtin_amdgcn_rcpf(x); }
// tanh(z) given zs = z*log2(e)
__device__ __forceinline__ float tanh2(float zs) { return 1.f - 2.f * frcp(1.f + fexp2(zs + zs)); }
__device__ __forceinline__ f32x2 exp2v(f32x2 x) { f32x2 r; r[0] = fexp2(x[0]); r[1] = fexp2(x[1]); return r; }
__device__ __forceinline__ f32x2 rcpv(f32x2 x)  { f32x2 r; r[0] = frcp(x[0]); r[1] = frcp(x[1]); return r; }

// round-to-nearest-even bf16, value in LOW 16 bits
__device__ __forceinline__ unsigned rnd_bf16(float w) {
  unsigned u = __float_as_uint(w);
  return (u + 0x7fffu + ((u >> 16) & 1u)) >> 16;
}
// packed f32->bf16x2 in ONE instruction: [bf16(a) | bf16(b)<<16]
__device__ __forceinline__ unsigned cvtpk(float a, float b) {
  unsigned r;
  asm("v_cvt_pk_bf16_f32 %0, %1, %2" : "=v"(r) : "v"(a), "v"(b));
  return r;
}

// Block = 8 waves = 4 layers x 2 hidden-halves, 16 batch rows/block.
// SWAPPED-OPERAND gates: C = mfma(A = W-tile, B = h) -> C[gate-unit][batch].
//   A-frag (W): lane(c,q): W row = 32g + 16hf + c, k = 8q+e  (PyTorch gate order i,f,g,o)
//   B-frag (h): lane(c,q): batch col = c, k (hidden unit) = 8q+e -> ONE ds_read_b128
//   C-frag:     lane(c,q): col = batch c, row = unit 16hf + 4q + e
// => lane's 4 gate/h outputs are 4 CONSECUTIVE units of one batch row: ONE ds_write_b64,
//    and the store layout IS the next step's B-frag read layout. 3 DS ops/wave/superstep.
// hb slots (bf16 [16 batch][32 units], 64B rows, 16B chunks XOR-swizzled by gcc(c)=(c&3)^(c>>2)):
//   slot k = h of layer k. Layer-0 input (emb) goes directly into B-frag regs from global.
// Attention on l=3 pair reusing fh: score = mfma(A=Wa replicated rows, B=fh) -> every
// elem = score(batch c); per-lane scalar online softmax; cx units split by hf from fh.
// Gate math packed f32; main-loop barrier = lgkmcnt-only; setprio around MFMA section.
__global__ __launch_bounds__(512, 4) void lstm_fused(
    const int* __restrict__ x, const float* __restrict__ emb,
    const float* __restrict__ Wih, const float* __restrict__ Whh,
    const float* __restrict__ bih, const float* __restrict__ bhh,
    const float* __restrict__ Wa, const float* __restrict__ W1,
    const float* __restrict__ b1, const float* __restrict__ W2,
    const float* __restrict__ b2, float* __restrict__ out)
{
  __shared__ __align__(16) unsigned short hb[2 * 4 * 512];  // [parity][slot][16][32] bf16

  const int tid  = threadIdx.x;
  const int wvu  = __builtin_amdgcn_readfirstlane(tid) >> 6;  // wave id 0..7 (SGPR)
  const int l    = wvu >> 1;       // layer 0..3
  const int hf   = wvu & 1;        // hidden half
  const int lane = tid & 63;
  const int c    = lane & 15;      // batch row (B/C col); W-tile row (A)
  const int q    = lane >> 4;
  const int gcc  = (c & 3) ^ (c >> 2);   // chunk swizzle for row c
  const int rowbase = blockIdx.x * 16;
  const int xrow = (rowbase + c) * TSEQ;

  // lane-static LDS offsets (in shorts)
  const int rdOff = c * 32 + ((q ^ gcc) << 3);   // B-frag read: units 8q..8q+7 of batch c
  const int wrOff = c * 32 + ((((2 * hf + (q >> 1)) ^ gcc) << 3) | ((q & 1) << 2));

  // ---- weights -> register-resident bf16 A-fragments (RTN), sign/scale folded
  FragU wihf[4], whhf[4];
#pragma unroll
  for (int g = 0; g < 4; ++g) {
    const float sj = (g == 2) ? TWO_L2E : -L2E;
    const int wr = 32 * g + 16 * hf + c;          // gate-dim row
    const float* srcI = Wih + l * 4096 + wr * 32 + 8 * q;
    const float* srcH = Whh + l * 4096 + wr * 32 + 8 * q;
#pragma unroll
    for (int p = 0; p < 4; ++p) {
      wihf[g].u[p] = rnd_bf16(srcI[2 * p] * sj) | (rnd_bf16(srcI[2 * p + 1] * sj) << 16);
      whhf[g].u[p] = rnd_bf16(srcH[2 * p] * sj) | (rnd_bf16(srcH[2 * p + 1] * sj) << 16);
    }
  }
  // biases as f32x4 C-operands: elem e = bias of unit 16hf+4q+e, gate g
  f32x4 bvv[4];
#pragma unroll
  for (int g = 0; g < 4; ++g) {
    const float sj = (g == 2) ? TWO_L2E : -L2E;
    const int bi = l * 128 + 32 * g + 16 * hf + 4 * q;
#pragma unroll
    for (int e = 0; e < 4; ++e)
      bvv[g][e] = (bih[bi + e] + bhh[bi + e]) * sj;
  }

  // ---- Wa as A-frag replicated over rows (l==3 waves), hi/lo split, scaled by log2e
  FragU wahA, walA;
#pragma unroll
  for (int p = 0; p < 4; ++p) { wahA.u[p] = 0u; walA.u[p] = 0u; }
  if (l == 3) {
#pragma unroll
    for (int p = 0; p < 4; ++p) {
      const int k0 = 8 * q + 2 * p;
      float w0 = Wa[k0] * L2E, w1 = Wa[k0 + 1] * L2E;
      unsigned h0 = rnd_bf16(w0), h1b = rnd_bf16(w1);
      wahA.u[p] = h0 | (h1b << 16);
      float l0v = w0 - __uint_as_float(h0 << 16);
      float l1v = w1 - __uint_as_float(h1b << 16);
      walA.u[p] = rnd_bf16(l0v) | (rnd_bf16(l1v) << 16);
    }
  }

  // per-lane state: cells for units 16hf+4q+e, batch c; attention (l==3)
  f32x2 cs2[2];
  cs2[0] = (f32x2){0.f, 0.f}; cs2[1] = (f32x2){0.f, 0.f};
  float mr = -1e30f, sr = 0.f, cx[4];
#pragma unroll
  for (int e = 0; e < 4; ++e) cx[e] = 0.f;

  // ---- zero LDS
  for (int i = tid; i < 2 * 4 * 512 / 2; i += 512) ((unsigned*)hb)[i] = 0u;

  // ---- l0 prologue: emb(0) -> regs; idxn = token(1)
  float4 emA = make_float4(0.f, 0.f, 0.f, 0.f), emB = emA;
  int idxn = 0;
  if (l == 0) {
    int i0 = x[xrow];
    emA = *(const float4*)(emb + i0 * 32 + 8 * q);
    emB = *(const float4*)(emb + i0 * 32 + 8 * q + 4);
    idxn = x[xrow + 1];
  }
  __syncthreads();

#pragma unroll 2
  for (int s = 0; s < TSEQ + 4; ++s) {
    const int t = s - l;
    const bool active = ((unsigned)t < (unsigned)TSEQ);
    const int rp = (s + 1) & 1;   // read parity
    const int wp = s & 1;         // write parity
    const bool doAtt = (l == 3) && (s >= 4);

    // ---- B-fragment acquire
    FragU fi, fh;
    __builtin_amdgcn_s_setprio(1);
    if (active) {
      if (l == 0) {
        // build fi from prefetched emb regs; then issue loads for t+1
        fi.u[0] = cvtpk(emA.x, emA.y); fi.u[1] = cvtpk(emA.z, emA.w);
        fi.u[2] = cvtpk(emB.x, emB.y); fi.u[3] = cvtpk(emB.z, emB.w);
        if (t + 1 < TSEQ) {
          emA = *(const float4*)(emb + idxn * 32 + 8 * q);
          emB = *(const float4*)(emb + idxn * 32 + 8 * q + 4);
        }
        if (t + 2 < TSEQ) idxn = x[xrow + t + 2];
      } else {
        fi.v = *(const uint4*)(hb + (rp * 4 + (l - 1)) * 512 + rdOff);
      }
    }
    if (active || doAtt)
      fh.v = *(const uint4*)(hb + (rp * 4 + l) * 512 + rdOff);

    // ---- gate MFMAs: C[gate-unit][batch] = W*x + W*h + bias
    f32x4 acc[4];
    if (active) {
#pragma unroll
      for (int g = 0; g < 4; ++g) {
        acc[g] = __builtin_amdgcn_mfma_f32_16x16x32_bf16(wihf[g].s, fi.s, bvv[g], 0, 0, 0);
        acc[g] = __builtin_amdgcn_mfma_f32_16x16x32_bf16(whhf[g].s, fh.s, acc[g], 0, 0, 0);
      }
    }
    // ---- attention score MFMAs (l=3, reuses fh = h3(t-1) B-frag)
    f32x4 sacc;
    if (doAtt) {
      f32x4 z = {0.f, 0.f, 0.f, 0.f};
      sacc = __builtin_amdgcn_mfma_f32_16x16x32_bf16(wahA.s, fh.s, z, 0, 0, 0);
      sacc = __builtin_amdgcn_mfma_f32_16x16x32_bf16(walA.s, fh.s, sacc, 0, 0, 0);
    }
    __builtin_amdgcn_s_setprio(0);

    if (active) {
      // ---- gates (packed f32): acc0=-zi*l2e acc1=-zf*l2e acc2=+2zg*l2e acc3=-zo*l2e
      float hv[4];
      const f32x2 one = {1.f, 1.f};
      const f32x2 tl2 = {TWO_L2E, TWO_L2E};
#pragma unroll
      for (int pr2 = 0; pr2 < 2; ++pr2) {
        const int e0 = 2 * pr2;
        f32x2 va; va[0] = acc[0][e0]; va[1] = acc[0][e0 + 1];
        f32x2 vm; vm[0] = acc[1][e0]; vm[1] = acc[1][e0 + 1];
        f32x2 vb; vb[0] = acc[2][e0]; vb[1] = acc[2][e0 + 1];
        f32x2 vp; vp[0] = acc[3][e0]; vp[1] = acc[3][e0 + 1];
        f32x2 ea = exp2v(va), em_ = exp2v(vm), eb = exp2v(vb), ep = exp2v(vp);
        f32x2 P  = (one + ea) * (one + eb);
        f32x2 M1 = one + em_;
        f32x2 num = cs2[pr2] * P + (eb - one) * M1;
        f32x2 cn = num * rcpv(M1 * P);
        cs2[pr2] = cn;
        f32x2 qa = cn * tl2;
        qa[0] = fminf(qa[0], 80.f); qa[1] = fminf(qa[1], 80.f);
        f32x2 qv = exp2v(qa);
        f32x2 hvv = (qv - one) * rcpv((one + ep) * (one + qv));
        hv[e0] = hvv[0]; hv[e0 + 1] = hvv[1];
      }

      // ---- write h(t): units 16hf+4q..+3 of batch c -> ONE ds_write_b64
      *(uint2*)(hb + (wp * 4 + l) * 512 + wrOff) =
          make_uint2(cvtpk(hv[0], hv[1]), cvtpk(hv[2], hv[3]));
    }

    // ---- attention online-softmax update (scalar per lane; score(batch c) in sacc[0])
    if (doAtt) {
      float pf = sacc[0];
      float mn = fmaxf(mr, pf);
      float sc = fexp2(mr - mn);
      float pr = fexp2(pf - mn);
      sr = sr * sc + pr;
      // this wave accumulates units 8q + 4hf .. +3 (elems 2hf,2hf+1 of fh)
#pragma unroll
      for (int p = 0; p < 2; ++p) {
        unsigned w = fh.u[2 * hf + p];
        float vlo = __uint_as_float(w << 16);
        float vhi = __uint_as_float(w & 0xffff0000u);
        cx[2 * p]     = cx[2 * p]     * sc + pr * vlo;
        cx[2 * p + 1] = cx[2 * p + 1] * sc + pr * vhi;
      }
      mr = mn;
    }

    // lgkm-only barrier: LDS synced; global prefetches stay in flight
    asm volatile("s_waitcnt lgkmcnt(0)\n\ts_barrier" ::: "memory");
  }

  __syncthreads();

  // ---- context -> LDS (fp32 [16][33]); l=3 waves: batch c, units 8q+4hf+e
  float* cb = (float*)hb;
  if (l == 3) {
    float inv = frcp(sr);
#pragma unroll
    for (int e = 0; e < 4; ++e)
      cb[c * 33 + 8 * q + 4 * hf + e] = cx[e] * inv;
  }
  __syncthreads();
  if (wvu != 6) return;

  // ---- head (single wave): tanh MLP -> out
  float a0[4], a1[4];
  {
    float bb0 = b1[c], bb1 = b1[c + 16];
#pragma unroll
    for (int e = 0; e < 4; ++e) { a0[e] = bb0; a1[e] = bb1; }
    for (int j = 0; j < 32; ++j) {
      float w0 = W1[j * 32 + c];
      float w1 = W1[j * 32 + c + 16];
#pragma unroll
      for (int e = 0; e < 4; ++e) {
        float cr = cb[(4 * q + e) * 33 + j];
        a0[e] = fmaf(cr, w0, a0[e]);
        a1[e] = fmaf(cr, w1, a1[e]);
      }
    }
  }
  float o0[4], o1[4], o2[4];
  {
    float w20 = W2[c * 3 + 0], w21 = W2[c * 3 + 1], w22 = W2[c * 3 + 2];
    float w30 = W2[(c + 16) * 3 + 0], w31 = W2[(c + 16) * 3 + 1], w32 = W2[(c + 16) * 3 + 2];
#pragma unroll
    for (int e = 0; e < 4; ++e) {
      float h0 = tanh2(a0[e] * L2E);
      float hB = tanh2(a1[e] * L2E);
      o0[e] = h0 * w20 + hB * w30;
      o1[e] = h0 * w21 + hB * w31;
      o2[e] = h0 * w22 + hB * w32;
    }
  }
#pragma unroll
  for (int mk = 1; mk <= 8; mk <<= 1) {
#pragma unroll
    for (int e = 0; e < 4; ++e) {
      o0[e] += __shfl_xor(o0[e], mk, 64);
      o1[e] += __shfl_xor(o1[e], mk, 64);
      o2[e] += __shfl_xor(o2[e], mk, 64);
    }
  }
  if (c < 3) {
    float bb = b2[c];
#pragma unroll
    for (int e = 0; e < 4; ++e) {
      float v = (c == 0) ? o0[e] : ((c == 1) ? o1[e] : o2[e]);
      out[(rowbase + 4 * q + e) * 3 + c] = v + bb;
    }
  }
}

extern "C" void kernel_launch(void* const* d_in, const int* in_sizes, int n_in,
                              void* d_out, int out_size, void* d_ws, size_t ws_size,
                              hipStream_t stream) {
  const int*   x   = (const int*)d_in[0];
  const float* emb = (const float*)d_in[1];
  const float* Wih = (const float*)d_in[2];
  const float* Whh = (const float*)d_in[3];
  const float* bih = (const float*)d_in[4];
  const float* bhh = (const float*)d_in[5];
  const float* Wa  = (const float*)d_in[6];
  // d_in[7] = ba: softmax is shift-invariant, so ba cancels exactly
  const float* W1  = (const float*)d_in[8];
  const float* b1  = (const float*)d_in[9];
  const float* W2  = (const float*)d_in[10];
  const float* b2  = (const float*)d_in[11];
  float* out = (float*)d_out;

  lstm_fused<<<512, 512, 0, stream>>>(x, emb, Wih, Whh, bih, bhh, Wa, W1, b1, W2, b2, out);
}